// Round 10
// baseline (304.061 us; speedup 1.0000x reference)
//
#include <hip/hip_runtime.h>
#include <hip/hip_bf16.h>
#include <math.h>

#define B_ 1024
#define M_ 16384
#define D_ 512
#define C_ 100
#define L_ 50

using short8  = __attribute__((ext_vector_type(8))) short;
using ushort8 = __attribute__((ext_vector_type(8))) unsigned short;
using f32x4   = __attribute__((ext_vector_type(4))) float;

__device__ inline void async16(const void* g, void* l) {
    __builtin_amdgcn_global_load_lds(
        (const __attribute__((address_space(1))) unsigned int*)g,
        (__attribute__((address_space(3))) unsigned int*)l, 16, 0, 0);
}

// ---------------- K_pre0: norms/bf16 + class bitmasks + counts + scores + zeros ---
__global__ __launch_bounds__(256) void k_pre0(
    const float* __restrict__ feat, const float* __restrict__ buf,
    const float* __restrict__ protos, const float* __restrict__ oldp,
    const int* __restrict__ lc, const int* __restrict__ blab,
    const float* __restrict__ W, const float* __restrict__ bbias,
    __hip_bfloat16* __restrict__ fbf, __hip_bfloat16* __restrict__ bbf,
    float* __restrict__ inv_feat, float* __restrict__ inv_np, float* __restrict__ inv_op,
    unsigned long long* __restrict__ maskT, int* __restrict__ cnt_buf,
    float* __restrict__ scores, float* __restrict__ acc,
    float* __restrict__ posS, float* __restrict__ negS) {
    const int P0 = B_ + M_ + 2 * L_;
    int b = blockIdx.x, t = threadIdx.x;
    if (b < P0) {
        const float* src; int row;
        __hip_bfloat16* dst = nullptr; float* ndst = nullptr;
        if (b < B_)                { src = feat;   row = b;                 dst = fbf + (size_t)b * D_; ndst = &inv_feat[b]; }
        else if (b < B_ + M_)      { int j = b - B_;           src = buf;    row = j;     dst = bbf + (size_t)j * D_; }
        else if (b < B_ + M_ + L_) { int j = b - B_ - M_;      src = protos; row = lc[j]; ndst = &inv_np[j]; }
        else                       { int j = b - B_ - M_ - L_; src = oldp;   row = lc[j]; ndst = &inv_op[j]; }
        const float* p = src + (size_t)row * D_;
        float v0 = p[t], v1 = p[t + 256];
        float ss = v0 * v0 + v1 * v1;
#pragma unroll
        for (int m = 32; m; m >>= 1) ss += __shfl_xor(ss, m);
        __shared__ float w4[4];
        if ((t & 63) == 0) w4[t >> 6] = ss;
        __syncthreads();
        float inv = 1.f / fmaxf(sqrtf(w4[0] + w4[1] + w4[2] + w4[3]), 1e-12f);
        if (dst) { dst[t] = __float2bfloat16(v0 * inv); dst[t + 256] = __float2bfloat16(v1 * inv); }
        if (ndst && t == 0) *ndst = inv;
    } else if (b < P0 + C_) {
        int c2 = b - P0;
        unsigned long long m = 0;
#pragma unroll
        for (int q = 0; q < 8; q++) {
            int base = q * 2048 + t * 8;
            int4 l0 = *(const int4*)(blab + base);
            int4 l1 = *(const int4*)(blab + base + 4);
            unsigned by = 0;
            by |= (unsigned)(l0.x == c2) << 0; by |= (unsigned)(l0.y == c2) << 1;
            by |= (unsigned)(l0.z == c2) << 2; by |= (unsigned)(l0.w == c2) << 3;
            by |= (unsigned)(l1.x == c2) << 4; by |= (unsigned)(l1.y == c2) << 5;
            by |= (unsigned)(l1.z == c2) << 6; by |= (unsigned)(l1.w == c2) << 7;
            m |= ((unsigned long long)by) << (8 * q);
        }
        maskT[(size_t)c2 * 256 + t] = m;
        int c = __popcll(m);
#pragma unroll
        for (int o = 32; o; o >>= 1) c += __shfl_xor(c, o);
        __shared__ int iw4[4];
        if ((t & 63) == 0) iw4[t >> 6] = c;
        __syncthreads();
        if (t == 0) cnt_buf[c2] = iw4[0] + iw4[1] + iw4[2] + iw4[3];
    } else {
        int bb2 = b - P0 - C_;
        if (bb2 == 0 && t < 8) acc[t] = 0.f;
        int wave = t >> 6, lane = t & 63;
        int row = bb2 * 4 + wave;
        const float* p = feat + (size_t)row * D_;
        float s = 0.f;
        for (int e = lane; e < D_; e += 64) s += p[e] * W[e];
#pragma unroll
        for (int off = 32; off > 0; off >>= 1) s += __shfl_down(s, off);
        if (lane == 0) {
            scores[row] = 1.f / (1.f + __expf(-(s + bbias[0])));
            posS[row] = 0.f;
            negS[row] = 0.f;
        }
    }
}

// ---------------- K2: bf16 MFMA GEMM -> keys + per-row pos/neg exp sums ----
#define TM 128
#define TN 128
#define TK 32
#define CPITCH 136
__global__ __launch_bounds__(256) void k_gemm(
    const __hip_bfloat16* __restrict__ A, const __hip_bfloat16* __restrict__ Bm,
    const int* __restrict__ labels, const int* __restrict__ blab,
    unsigned short* __restrict__ keys,
    float* __restrict__ posS, float* __restrict__ negS) {
    __shared__ unsigned short smem[TM * CPITCH];
    unsigned short* As = smem;
    unsigned short* Bs = smem + TM * TK;
    int t = threadIdx.x;
    int wave = t >> 6, lane = t & 63;
    int row0 = blockIdx.y * TM;
    int col0 = blockIdx.x * TN;
    int c0 = t, c1 = t + 256;
    const ushort* Ag0 = (const ushort*)A + (size_t)(row0 + (c0 >> 2)) * D_ + (c0 & 3) * 8;
    const ushort* Ag1 = (const ushort*)A + (size_t)(row0 + (c1 >> 2)) * D_ + (c1 & 3) * 8;
    const ushort* Bg0 = (const ushort*)Bm + (size_t)(col0 + (c0 >> 2)) * D_ + (c0 & 3) * 8;
    const ushort* Bg1 = (const ushort*)Bm + (size_t)(col0 + (c1 >> 2)) * D_ + (c1 & 3) * 8;
    unsigned short* As0 = &As[c0 * 8]; unsigned short* As1 = &As[c1 * 8];
    unsigned short* Bs0 = &Bs[c0 * 8]; unsigned short* Bs1 = &Bs[c1 * 8];
    int wm = (wave & 1) * 64, wn = (wave >> 1) * 64;
    f32x4 acc[4][4];
#pragma unroll
    for (int i = 0; i < 4; i++)
#pragma unroll
        for (int j = 0; j < 4; j++) acc[i][j] = {0.f, 0.f, 0.f, 0.f};
    int fr = lane & 15, fk = (lane >> 4) * 8;
    for (int k0 = 0; k0 < D_; k0 += TK) {
        async16(Ag0 + k0, As0);
        async16(Ag1 + k0, As1);
        async16(Bg0 + k0, Bs0);
        async16(Bg1 + k0, Bs1);
        __syncthreads();
        short8 af[4], bf2[4];
#pragma unroll
        for (int i = 0; i < 4; i++)
            af[i] = *(const short8*)&As[(wm + i * 16 + fr) * TK + fk];
#pragma unroll
        for (int j = 0; j < 4; j++)
            bf2[j] = *(const short8*)&Bs[(wn + j * 16 + fr) * TK + fk];
#pragma unroll
        for (int i = 0; i < 4; i++)
#pragma unroll
            for (int j = 0; j < 4; j++)
                acc[i][j] = __builtin_amdgcn_mfma_f32_16x16x32_bf16(af[i], bf2[j], acc[i][j], 0, 0, 0);
        __syncthreads();
    }
    int quad = lane >> 4, cpos = lane & 15;
    // column buffer-labels for this thread's 4 columns
    int blJ0 = blab[col0 + wn + 0 * 16 + cpos];
    int blJ1 = blab[col0 + wn + 1 * 16 + cpos];
    int blJ2 = blab[col0 + wn + 2 * 16 + cpos];
    int blJ3 = blab[col0 + wn + 3 * 16 + cpos];
#pragma unroll
    for (int i = 0; i < 4; i++) {
        int4 L = *(const int4*)&labels[row0 + wm + i * 16 + quad * 4];
#pragma unroll
        for (int r = 0; r < 4; r++) {
            int lr = (r == 0) ? L.x : (r == 1) ? L.y : (r == 2) ? L.z : L.w;
            int grow = row0 + wm + i * 16 + quad * 4 + r;
            float ps = 0.f, ns = 0.f;
#pragma unroll
            for (int j = 0; j < 4; j++) {
                int bl = (j == 0) ? blJ0 : (j == 1) ? blJ1 : (j == 2) ? blJ2 : blJ3;
                int lc2 = wn + j * 16 + cpos;
                float v = fminf(fmaxf(acc[i][j][r] * 5.0f, -10.f), 10.f);
                unsigned u = __float_as_uint(v);
                unsigned bits = (u + 0x7FFFu + ((u >> 16) & 1u)) >> 16;   // RNE bf16
                unsigned key = (bits & 0x8000u) ? (~bits & 0xFFFFu) : (bits | 0x8000u);
                smem[(wm + i * 16 + quad * 4 + r) * CPITCH + lc2] = (unsigned short)key;
                float e = __expf(__uint_as_float(bits << 16));  // exp of bf16-rounded sim
                if (bl == lr) ps += e; else ns += e;
            }
            // reduce over the 16 lanes (cpos) sharing this row
#pragma unroll
            for (int o = 8; o; o >>= 1) { ps += __shfl_xor(ps, o); ns += __shfl_xor(ns, o); }
            if (cpos == 0) {
                atomicAdd(&posS[grow], ps);
                atomicAdd(&negS[grow], ns);
            }
        }
    }
    __syncthreads();
    int lr3 = t >> 4, lc3 = (t & 15) * 8;
#pragma unroll
    for (int p = 0; p < 8; p++) {
        int row = p * 16 + lr3;
        uint4 kv = *(const uint4*)&smem[row * CPITCH + lc3];
        *(uint4*)&keys[(size_t)(row0 + row) * M_ + col0 + lc3] = kv;
    }
}

// ---------------- K3: saturation-certified fast path + exact bisection fallback ----
__device__ inline float keyval(unsigned key) {
    unsigned bits = (key & 0x8000u) ? (key ^ 0x8000u) : (~key & 0xFFFFu);
    return __uint_as_float(bits << 16);
}

__global__ __launch_bounds__(256) void k_select(
    const unsigned short* __restrict__ keys, const int* __restrict__ labels,
    const unsigned long long* __restrict__ maskT, const int* __restrict__ cnt_buf,
    const float* __restrict__ posS, const float* __restrict__ negS,
    float* __restrict__ acc) {
    __shared__ unsigned sku[8192];
    __shared__ int warr[16][4];
    __shared__ float rP[4], rS[4]; __shared__ int rC[4];
    __shared__ int skipFlag;
    int row = blockIdx.x;
    int t = threadIdx.x;
    int wave = t >> 6;
    int lab = labels[row];

    if (t == 0) {
        int n_pos = cnt_buf[lab];
        int n_neg = M_ - n_pos;
        int k = (int)(0.7f * (float)n_neg);
        int skip = 0;
        if (n_pos <= 0 || k <= 0) {
            skip = 1;   // valid=0: row contributes nothing (matches reference)
        } else {
            float pos_exp = posS[row] / (float)n_pos;
            // rigorous lower bound: top-k sum >= (k/n)*total for nonneg values
            float neg_lb = negS[row] * ((float)k / (float)n_neg);
            float ratio_ub = pos_exp / (pos_exp + neg_lb);
            if (ratio_ub < 6.0e-3f) {   // < e^-5=6.7379e-3 with margin -> loss==5.0 exactly
                atomicAdd(&acc[0], 5.0f);
                atomicAdd(&acc[1], 1.0f);
                skip = 1;
            }
        }
        skipFlag = skip;
    }
    __syncthreads();
    if (skipFlag) return;

    // ---- exact fallback: LDS-staged 16-round bisection (verified rounds 8-9) ----
    unsigned long long pm = maskT[(size_t)lab * 256 + t];
    const unsigned short* kr = keys + (size_t)row * M_ + t * 8;
#pragma unroll
    for (int q = 0; q < 8; q++)
        async16(kr + q * 2048, &sku[(q * 256 + t) * 4]);
    __syncthreads();

    float pp = 0.f;
#pragma unroll
    for (int q = 0; q < 8; q++) {
        unsigned pb = (unsigned)(pm >> (8 * q)) & 0xFFu;
        while (pb) {
            int b = __ffs(pb) - 1; pb &= pb - 1;
            unsigned idx = (unsigned)(q * 256 + t) * 4 + (b >> 1);
            unsigned w = sku[idx];
            unsigned key = (b & 1) ? (w >> 16) : (w & 0xFFFFu);
            pp += __expf(keyval(key));
            sku[idx] = (b & 1) ? (w & 0x0000FFFFu) : (w & 0xFFFF0000u);
        }
    }

    int n_pos = cnt_buf[lab];
    int k = (int)(0.7f * (float)(M_ - n_pos));

    unsigned cur = 0;
    for (int r = 15; r >= 0; r--) {
        unsigned T = cur | (1u << r);
        unsigned Th = T << 16;
        int cnt = 0;
#pragma unroll
        for (int q = 0; q < 8; q++) {
            uint4 w = *(const uint4*)&sku[(unsigned)(q * 256 + t) * 4];
            cnt += __popcll(__ballot(w.x >= Th)) + __popcll(__ballot((w.x & 0xFFFFu) >= T));
            cnt += __popcll(__ballot(w.y >= Th)) + __popcll(__ballot((w.y & 0xFFFFu) >= T));
            cnt += __popcll(__ballot(w.z >= Th)) + __popcll(__ballot((w.z & 0xFFFFu) >= T));
            cnt += __popcll(__ballot(w.w >= Th)) + __popcll(__ballot((w.w & 0xFFFFu) >= T));
        }
        if ((t & 63) == 0) warr[15 - r][wave] = cnt;
        __syncthreads();
        int tot = warr[15 - r][0] + warr[15 - r][1] + warr[15 - r][2] + warr[15 - r][3];
        if (tot >= k) cur = T;
    }

    int cgt = 0; float sgt = 0.f;
#pragma unroll
    for (int q = 0; q < 8; q++) {
        uint4 w = *(const uint4*)&sku[(unsigned)(q * 256 + t) * 4];
#define HALVES(x)                                                              \
        { unsigned hk = (x) >> 16;    if (hk > cur) { cgt++; sgt += __expf(keyval(hk)); } \
          unsigned lk = (x) & 0xFFFFu; if (lk > cur) { cgt++; sgt += __expf(keyval(lk)); } }
        HALVES(w.x) HALVES(w.y) HALVES(w.z) HALVES(w.w)
#undef HALVES
    }

#pragma unroll
    for (int o = 32; o; o >>= 1) {
        pp  += __shfl_xor(pp, o);
        sgt += __shfl_xor(sgt, o);
        cgt += __shfl_xor(cgt, o);
    }
    if ((t & 63) == 0) { rP[wave] = pp; rS[wave] = sgt; rC[wave] = cgt; }
    __syncthreads();
    if (t == 0) {
        float posAcc = rP[0] + rP[1] + rP[2] + rP[3];
        float sumGt  = rS[0] + rS[1] + rS[2] + rS[3];
        int   cntGt  = rC[0] + rC[1] + rC[2] + rC[3];
        float negExp = 0.f;
        if (k > 0) negExp = sumGt + (float)(k - cntGt) * __expf(keyval(cur));
        float pos_exp = posAcc / (float)max(n_pos, 1);
        int valid = (k > 0 && n_pos > 0) ? 1 : 0;
        float denom = fmaxf(pos_exp + negExp, 1e-8f);
        float ratio = fminf(fmaxf(pos_exp / denom, 1e-8f), 1.0f);
        float loss = fminf(fmaxf(-logf(ratio), 0.f), 5.f);
        if (valid) { atomicAdd(&acc[0], loss); atomicAdd(&acc[1], 1.f); }
    }
}

// ---------------- K_tail: class boundary stats (compacted) + PRD KL ----------------
__global__ __launch_bounds__(256) void k_tail(
    const float* __restrict__ F, const int* __restrict__ labels,
    const float* __restrict__ scores,
    const float* __restrict__ protos, const float* __restrict__ oldp,
    const int* __restrict__ lc, const float* __restrict__ inv_f,
    const float* __restrict__ inv_np, const float* __restrict__ inv_op,
    float* __restrict__ acc) {
    int b = blockIdx.x, t = threadIdx.x;
    if (b < C_) {
        int c = b;
        __shared__ int list[B_];
        __shared__ int cnt;
        if (t == 0) cnt = 0;
        __syncthreads();
        for (int i = t; i < B_; i += 256)
            if (labels[i] == c) { int pos = atomicAdd(&cnt, 1); list[pos] = i; }
        __syncthreads();
        int n = cnt;
        float s0 = 0.f, s1 = 0.f, q0 = 0.f, q1 = 0.f, sc = 0.f;
        for (int j = 0; j < n; j++) {
            int r = list[j];
            const float* p = F + (size_t)r * D_;
            float v0 = p[t], v1 = p[t + 256];
            s0 += v0; s1 += v1; q0 += v0 * v0; q1 += v1 * v1;
        }
        for (int j = t; j < n; j += 256) sc += scores[list[j]];
        float fn = (float)n;
        float safe_n = fmaxf(fn, 1.f);
        float m0 = s0 / safe_n, m1 = s1 / safe_n;
        float dv = fmaxf(fn - 1.f, 1.f);
        float v0 = (q0 - fn * m0 * m0) / dv;
        float v1 = (q1 - fn * m1 * m1) / dv;
        float rv = v0 + v1;
#pragma unroll
        for (int o = 32; o; o >>= 1) { rv += __shfl_xor(rv, o); sc += __shfl_xor(sc, o); }
        __shared__ float wv[4], wsc[4];
        if ((t & 63) == 0) { wv[t >> 6] = rv; wsc[t >> 6] = sc; }
        __syncthreads();
        if (t == 0) {
            float var_mean = (wv[0] + wv[1] + wv[2] + wv[3]) / 512.f;
            var_mean = fminf(fmaxf(var_mean, 1e-6f), 100.f);
            float target = 1.f / (1.f + expf(-var_mean));
            float mean_s = (wsc[0] + wsc[1] + wsc[2] + wsc[3]) / safe_n;
            float d = mean_s - target;
            float bl = fminf(d * d, 2.f);
            if (fn > 1.f) { atomicAdd(&acc[2], bl); atomicAdd(&acc[3], 1.f); }
        }
    } else {
        int row = b - C_;
        __shared__ float f[D_];
        __shared__ float so[L_], sn[L_];
        float invf = inv_f[row] * 5.0f;
        const float* p = F + (size_t)row * D_;
        f[t] = p[t]; f[t + 256] = p[t + 256];
        __syncthreads();
        int wave = t >> 6, lane = t & 63;
        for (int j = wave; j < 2 * L_; j += 4) {
            int idx = (j < L_) ? j : j - L_;
            const float* P = ((j < L_) ? oldp : protos) + (size_t)lc[idx] * D_;
            float inv = (j < L_) ? inv_op[idx] : inv_np[idx];
            float s = 0.f;
            for (int e = lane; e < D_; e += 64) s += f[e] * P[e];
#pragma unroll
            for (int off = 32; off > 0; off >>= 1) s += __shfl_down(s, off);
            if (lane == 0) {
                float v = fminf(fmaxf(s * invf * inv, -10.f), 10.f);
                if (j < L_) so[idx] = v; else sn[idx] = v;
            }
        }
        __syncthreads();
        if (t == 0) {
            float mo = -1e30f, mn = -1e30f;
            for (int i = 0; i < L_; i++) { mo = fmaxf(mo, so[i]); mn = fmaxf(mn, sn[i]); }
            float eo = 0.f, en = 0.f;
            for (int i = 0; i < L_; i++) { eo += __expf(so[i] - mo); en += __expf(sn[i] - mn); }
            float lo = logf(eo), ln_ = logf(en);
            float kl = 0.f;
            for (int i = 0; i < L_; i++) {
                float olp = so[i] - mo - lo;
                float nlp = sn[i] - mn - ln_;
                kl += __expf(olp) * (olp - nlp);
            }
            atomicAdd(&acc[4], kl);
        }
    }
}

// ---------------- K_final: combine ----------------
__global__ void k_final(const float* __restrict__ acc, float* __restrict__ out) {
    float hard = acc[0] / fmaxf(acc[1], 1.f);
    float boundary = acc[2] / fmaxf(acc[3], 1.f);
    float kl = fminf(fmaxf(acc[4] / (float)B_, 0.f), 5.f);
    out[0] = hard + 0.1f * boundary + 0.2f * kl;
}

extern "C" void kernel_launch(void* const* d_in, const int* in_sizes, int n_in,
                              void* d_out, int out_size, void* d_ws, size_t ws_size,
                              hipStream_t stream) {
    const float* feat   = (const float*)d_in[0];
    const float* buf    = (const float*)d_in[1];
    const float* protos = (const float*)d_in[2];
    const float* oldp   = (const float*)d_in[3];
    const float* W      = (const float*)d_in[4];
    const float* bb     = (const float*)d_in[5];
    const int* labels   = (const int*)d_in[6];
    const int* blab     = (const int*)d_in[7];
    const int* lc       = (const int*)d_in[8];
    float* out = (float*)d_out;

    char* wsb = (char*)d_ws;
    unsigned short* keyb = (unsigned short*)wsb;                        // 32 MiB
    __hip_bfloat16* fbf  = (__hip_bfloat16*)(wsb + 33554432);           // 1 MiB
    __hip_bfloat16* bbf  = (__hip_bfloat16*)(wsb + 34603008);           // 16 MiB
    unsigned long long* maskT = (unsigned long long*)(wsb + 51380224);  // 200 KiB
    float* inv_feat = (float*)(wsb + 51380224 + 204800);
    float* inv_np   = inv_feat + B_;
    float* inv_op   = inv_np + L_;
    float* scores   = inv_op + L_;
    int*   cnt_buf  = (int*)(scores + B_);
    float* acc      = (float*)(cnt_buf + 128);
    float* posS     = acc + 8;
    float* negS     = posS + B_;

    const int P0 = B_ + M_ + 2 * L_;
    k_pre0<<<P0 + C_ + B_ / 4, 256, 0, stream>>>(feat, buf, protos, oldp, lc, blab, W, bb,
                                                 fbf, bbf, inv_feat, inv_np, inv_op,
                                                 maskT, cnt_buf, scores, acc, posS, negS);
    dim3 g(M_ / TN, B_ / TM);
    k_gemm<<<g, 256, 0, stream>>>(fbf, bbf, labels, blab, keyb, posS, negS);
    k_select<<<B_, 256, 0, stream>>>(keyb, labels, maskT, cnt_buf, posS, negS, acc);
    k_tail<<<C_ + B_, 256, 0, stream>>>(feat, labels, scores, protos, oldp, lc,
                                        inv_feat, inv_np, inv_op, acc);
    k_final<<<1, 1, 0, stream>>>(acc, out);
}

// Round 11
// 203.626 us; speedup vs baseline: 1.4932x; 1.4932x over previous
//
#include <hip/hip_runtime.h>
#include <hip/hip_bf16.h>
#include <math.h>

#define B_ 1024
#define M_ 16384
#define D_ 512
#define C_ 100
#define L_ 50

using short8  = __attribute__((ext_vector_type(8))) short;
using ushort8 = __attribute__((ext_vector_type(8))) unsigned short;
using f32x4   = __attribute__((ext_vector_type(4))) float;

__device__ inline void async16(const void* g, void* l) {
    __builtin_amdgcn_global_load_lds(
        (const __attribute__((address_space(1))) unsigned int*)g,
        (__attribute__((address_space(3))) unsigned int*)l, 16, 0, 0);
}

// ---------------- K_pre0: norms/bf16 + class bitmasks + counts + scores + acc zero ---
__global__ __launch_bounds__(256) void k_pre0(
    const float* __restrict__ feat, const float* __restrict__ buf,
    const float* __restrict__ protos, const float* __restrict__ oldp,
    const int* __restrict__ lc, const int* __restrict__ blab,
    const float* __restrict__ W, const float* __restrict__ bbias,
    __hip_bfloat16* __restrict__ fbf, __hip_bfloat16* __restrict__ bbf,
    float* __restrict__ inv_feat, float* __restrict__ inv_np, float* __restrict__ inv_op,
    unsigned long long* __restrict__ maskT, int* __restrict__ cnt_buf,
    float* __restrict__ scores, float* __restrict__ acc) {
    const int P0 = B_ + M_ + 2 * L_;
    int b = blockIdx.x, t = threadIdx.x;
    if (b < P0) {
        const float* src; int row;
        __hip_bfloat16* dst = nullptr; float* ndst = nullptr;
        if (b < B_)                { src = feat;   row = b;                 dst = fbf + (size_t)b * D_; ndst = &inv_feat[b]; }
        else if (b < B_ + M_)      { int j = b - B_;           src = buf;    row = j;     dst = bbf + (size_t)j * D_; }
        else if (b < B_ + M_ + L_) { int j = b - B_ - M_;      src = protos; row = lc[j]; ndst = &inv_np[j]; }
        else                       { int j = b - B_ - M_ - L_; src = oldp;   row = lc[j]; ndst = &inv_op[j]; }
        const float* p = src + (size_t)row * D_;
        float v0 = p[t], v1 = p[t + 256];
        float ss = v0 * v0 + v1 * v1;
#pragma unroll
        for (int m = 32; m; m >>= 1) ss += __shfl_xor(ss, m);
        __shared__ float w4[4];
        if ((t & 63) == 0) w4[t >> 6] = ss;
        __syncthreads();
        float inv = 1.f / fmaxf(sqrtf(w4[0] + w4[1] + w4[2] + w4[3]), 1e-12f);
        if (dst) { dst[t] = __float2bfloat16(v0 * inv); dst[t + 256] = __float2bfloat16(v1 * inv); }
        if (ndst && t == 0) *ndst = inv;
    } else if (b < P0 + C_) {
        int c2 = b - P0;
        unsigned long long m = 0;
#pragma unroll
        for (int q = 0; q < 8; q++) {
            int base = q * 2048 + t * 8;
            int4 l0 = *(const int4*)(blab + base);
            int4 l1 = *(const int4*)(blab + base + 4);
            unsigned by = 0;
            by |= (unsigned)(l0.x == c2) << 0; by |= (unsigned)(l0.y == c2) << 1;
            by |= (unsigned)(l0.z == c2) << 2; by |= (unsigned)(l0.w == c2) << 3;
            by |= (unsigned)(l1.x == c2) << 4; by |= (unsigned)(l1.y == c2) << 5;
            by |= (unsigned)(l1.z == c2) << 6; by |= (unsigned)(l1.w == c2) << 7;
            m |= ((unsigned long long)by) << (8 * q);
        }
        maskT[(size_t)c2 * 256 + t] = m;
        int c = __popcll(m);
#pragma unroll
        for (int o = 32; o; o >>= 1) c += __shfl_xor(c, o);
        __shared__ int iw4[4];
        if ((t & 63) == 0) iw4[t >> 6] = c;
        __syncthreads();
        if (t == 0) cnt_buf[c2] = iw4[0] + iw4[1] + iw4[2] + iw4[3];
    } else {
        int bb2 = b - P0 - C_;
        if (bb2 == 0 && t < 8) acc[t] = 0.f;
        int wave = t >> 6, lane = t & 63;
        int row = bb2 * 4 + wave;
        const float* p = feat + (size_t)row * D_;
        float s = 0.f;
        for (int e = lane; e < D_; e += 64) s += p[e] * W[e];
#pragma unroll
        for (int off = 32; off > 0; off >>= 1) s += __shfl_down(s, off);
        if (lane == 0) scores[row] = 1.f / (1.f + __expf(-(s + bbias[0])));
    }
}

// ---------------- K2: bf16 MFMA GEMM -> 16-bit sort keys (coalesced stores) ----
// clean round-6 version: NO label loads, NO reductions in epilogue (rule: never
// fuse reductions into the GEMM epilogue — rounds 4 & 10 both regressed ~2.5x).
#define TM 128
#define TN 128
#define TK 32
#define CPITCH 136
__global__ __launch_bounds__(256) void k_gemm(
    const __hip_bfloat16* __restrict__ A, const __hip_bfloat16* __restrict__ Bm,
    unsigned short* __restrict__ keys) {
    __shared__ unsigned short smem[TM * CPITCH];
    unsigned short* As = smem;
    unsigned short* Bs = smem + TM * TK;
    int t = threadIdx.x;
    int wave = t >> 6, lane = t & 63;
    int row0 = blockIdx.y * TM;
    int col0 = blockIdx.x * TN;
    int c0 = t, c1 = t + 256;
    const ushort* Ag0 = (const ushort*)A + (size_t)(row0 + (c0 >> 2)) * D_ + (c0 & 3) * 8;
    const ushort* Ag1 = (const ushort*)A + (size_t)(row0 + (c1 >> 2)) * D_ + (c1 & 3) * 8;
    const ushort* Bg0 = (const ushort*)Bm + (size_t)(col0 + (c0 >> 2)) * D_ + (c0 & 3) * 8;
    const ushort* Bg1 = (const ushort*)Bm + (size_t)(col0 + (c1 >> 2)) * D_ + (c1 & 3) * 8;
    unsigned short* As0 = &As[c0 * 8]; unsigned short* As1 = &As[c1 * 8];
    unsigned short* Bs0 = &Bs[c0 * 8]; unsigned short* Bs1 = &Bs[c1 * 8];
    int wm = (wave & 1) * 64, wn = (wave >> 1) * 64;
    f32x4 acc[4][4];
#pragma unroll
    for (int i = 0; i < 4; i++)
#pragma unroll
        for (int j = 0; j < 4; j++) acc[i][j] = {0.f, 0.f, 0.f, 0.f};
    int fr = lane & 15, fk = (lane >> 4) * 8;
    for (int k0 = 0; k0 < D_; k0 += TK) {
        async16(Ag0 + k0, As0);
        async16(Ag1 + k0, As1);
        async16(Bg0 + k0, Bs0);
        async16(Bg1 + k0, Bs1);
        __syncthreads();
        short8 af[4], bf2[4];
#pragma unroll
        for (int i = 0; i < 4; i++)
            af[i] = *(const short8*)&As[(wm + i * 16 + fr) * TK + fk];
#pragma unroll
        for (int j = 0; j < 4; j++)
            bf2[j] = *(const short8*)&Bs[(wn + j * 16 + fr) * TK + fk];
#pragma unroll
        for (int i = 0; i < 4; i++)
#pragma unroll
            for (int j = 0; j < 4; j++)
                acc[i][j] = __builtin_amdgcn_mfma_f32_16x16x32_bf16(af[i], bf2[j], acc[i][j], 0, 0, 0);
        __syncthreads();
    }
    int quad = lane >> 4, cpos = lane & 15;
#pragma unroll
    for (int i = 0; i < 4; i++)
#pragma unroll
        for (int j = 0; j < 4; j++)
#pragma unroll
            for (int r = 0; r < 4; r++) {
                int lr2 = wm + i * 16 + quad * 4 + r;
                int lc2 = wn + j * 16 + cpos;
                float v = fminf(fmaxf(acc[i][j][r] * 5.0f, -10.f), 10.f);
                unsigned u = __float_as_uint(v);
                unsigned bits = (u + 0x7FFFu + ((u >> 16) & 1u)) >> 16;   // RNE bf16
                unsigned key = (bits & 0x8000u) ? (~bits & 0xFFFFu) : (bits | 0x8000u);
                smem[lr2 * CPITCH + lc2] = (unsigned short)key;
            }
    __syncthreads();
    int lr3 = t >> 4, lc3 = (t & 15) * 8;
#pragma unroll
    for (int p = 0; p < 8; p++) {
        int row = p * 16 + lr3;
        uint4 kv = *(const uint4*)&smem[row * CPITCH + lc3];
        *(uint4*)&keys[(size_t)(row0 + row) * M_ + col0 + lc3] = kv;
    }
}

// ---------------- K3: stage->sums->saturation cert; exact bisection fallback ----
__device__ inline float keyval(unsigned key) {
    unsigned bits = (key & 0x8000u) ? (key ^ 0x8000u) : (~key & 0xFFFFu);
    return __uint_as_float(bits << 16);
}

__global__ __launch_bounds__(256) void k_select(
    const unsigned short* __restrict__ keys, const int* __restrict__ labels,
    const unsigned long long* __restrict__ maskT, const int* __restrict__ cnt_buf,
    float* __restrict__ acc) {
    __shared__ unsigned sku[8192];          // 32 KB: this row's 16384 keys
    __shared__ int warr[16][4];
    __shared__ float rT[4], rP[4], rS[4]; __shared__ int rC[4];
    int row = blockIdx.x;
    int t = threadIdx.x;
    int wave = t >> 6;
    int lab = labels[row];
    unsigned long long pm = maskT[(size_t)lab * 256 + t];
    const unsigned short* kr = keys + (size_t)row * M_ + t * 8;

    // stage direct to LDS (wave-uniform base + lane*16 slots)
#pragma unroll
    for (int q = 0; q < 8; q++)
        async16(kr + q * 2048, &sku[(q * 256 + t) * 4]);
    __syncthreads();

    // total exp over own slots (includes positives for now)
    float tot = 0.f;
#pragma unroll
    for (int q = 0; q < 8; q++) {
        uint4 w = *(const uint4*)&sku[(unsigned)(q * 256 + t) * 4];
#define TSUM(x) tot += __expf(keyval((x) >> 16)) + __expf(keyval((x) & 0xFFFFu));
        TSUM(w.x) TSUM(w.y) TSUM(w.z) TSUM(w.w)
#undef TSUM
    }
    // positive fixup: accumulate pos exp, zero those slots (rare)
    float pp = 0.f;
#pragma unroll
    for (int q = 0; q < 8; q++) {
        unsigned pb = (unsigned)(pm >> (8 * q)) & 0xFFu;
        while (pb) {
            int b = __ffs(pb) - 1; pb &= pb - 1;
            unsigned idx = (unsigned)(q * 256 + t) * 4 + (b >> 1);
            unsigned w = sku[idx];
            unsigned key = (b & 1) ? (w >> 16) : (w & 0xFFFFu);
            pp += __expf(keyval(key));
            sku[idx] = (b & 1) ? (w & 0x0000FFFFu) : (w & 0xFFFF0000u);
        }
    }
#pragma unroll
    for (int o = 32; o; o >>= 1) { tot += __shfl_xor(tot, o); pp += __shfl_xor(pp, o); }
    if ((t & 63) == 0) { rT[wave] = tot; rP[wave] = pp; }
    __syncthreads();
    float TOT = rT[0] + rT[1] + rT[2] + rT[3];
    float PP  = rP[0] + rP[1] + rP[2] + rP[3];

    int n_pos = cnt_buf[lab];
    int n_neg = M_ - n_pos;
    int k = (int)(0.7f * (float)n_neg);   // fp32-mul + trunc matches reference

    // saturation certificate (uniform across block):
    // top-k sum of nonneg values >= (k/n_neg)*total  =>  ratio_ub >= true ratio
    int skip = 0;
    if (n_pos <= 0 || k <= 0) {
        skip = 1;                          // valid=0: contributes nothing
    } else {
        float pos_exp = PP / (float)n_pos;
        float neg_lb = (TOT - PP) * ((float)k / (float)n_neg);
        float ratio_ub = pos_exp / (pos_exp + neg_lb);
        if (ratio_ub < 6.0e-3f) {          // < e^-5 = 6.7379e-3, margin 25x -> loss==5.0
            if (t == 0) { atomicAdd(&acc[0], 5.0f); atomicAdd(&acc[1], 1.0f); }
            skip = 1;
        }
    }
    if (skip) return;

    // ---- exact fallback: 16-round bisection on LDS keys (positives already zeroed) ----
    unsigned cur = 0;
    for (int r = 15; r >= 0; r--) {
        unsigned T = cur | (1u << r);
        unsigned Th = T << 16;
        int cnt = 0;
#pragma unroll
        for (int q = 0; q < 8; q++) {
            uint4 w = *(const uint4*)&sku[(unsigned)(q * 256 + t) * 4];
            cnt += __popcll(__ballot(w.x >= Th)) + __popcll(__ballot((w.x & 0xFFFFu) >= T));
            cnt += __popcll(__ballot(w.y >= Th)) + __popcll(__ballot((w.y & 0xFFFFu) >= T));
            cnt += __popcll(__ballot(w.z >= Th)) + __popcll(__ballot((w.z & 0xFFFFu) >= T));
            cnt += __popcll(__ballot(w.w >= Th)) + __popcll(__ballot((w.w & 0xFFFFu) >= T));
        }
        if ((t & 63) == 0) warr[15 - r][wave] = cnt;
        __syncthreads();
        int tot2 = warr[15 - r][0] + warr[15 - r][1] + warr[15 - r][2] + warr[15 - r][3];
        if (tot2 >= k) cur = T;
    }

    int cgt = 0; float sgt = 0.f;
#pragma unroll
    for (int q = 0; q < 8; q++) {
        uint4 w = *(const uint4*)&sku[(unsigned)(q * 256 + t) * 4];
#define HALVES(x)                                                              \
        { unsigned hk = (x) >> 16;    if (hk > cur) { cgt++; sgt += __expf(keyval(hk)); } \
          unsigned lk = (x) & 0xFFFFu; if (lk > cur) { cgt++; sgt += __expf(keyval(lk)); } }
        HALVES(w.x) HALVES(w.y) HALVES(w.z) HALVES(w.w)
#undef HALVES
    }
#pragma unroll
    for (int o = 32; o; o >>= 1) { sgt += __shfl_xor(sgt, o); cgt += __shfl_xor(cgt, o); }
    if ((t & 63) == 0) { rS[wave] = sgt; rC[wave] = cgt; }
    __syncthreads();
    if (t == 0) {
        float sumGt = rS[0] + rS[1] + rS[2] + rS[3];
        int   cntGt = rC[0] + rC[1] + rC[2] + rC[3];
        float negExp = sumGt + (float)(k - cntGt) * __expf(keyval(cur));
        float pos_exp = PP / (float)max(n_pos, 1);
        float denom = fmaxf(pos_exp + negExp, 1e-8f);
        float ratio = fminf(fmaxf(pos_exp / denom, 1e-8f), 1.0f);
        float loss = fminf(fmaxf(-logf(ratio), 0.f), 5.f);
        atomicAdd(&acc[0], loss); atomicAdd(&acc[1], 1.f);
    }
}

// ---------------- K_tail: class boundary stats (compacted) + PRD KL ----------------
__global__ __launch_bounds__(256) void k_tail(
    const float* __restrict__ F, const int* __restrict__ labels,
    const float* __restrict__ scores,
    const float* __restrict__ protos, const float* __restrict__ oldp,
    const int* __restrict__ lc, const float* __restrict__ inv_f,
    const float* __restrict__ inv_np, const float* __restrict__ inv_op,
    float* __restrict__ acc) {
    int b = blockIdx.x, t = threadIdx.x;
    if (b < C_) {
        int c = b;
        __shared__ int list[B_];
        __shared__ int cnt;
        if (t == 0) cnt = 0;
        __syncthreads();
        for (int i = t; i < B_; i += 256)
            if (labels[i] == c) { int pos = atomicAdd(&cnt, 1); list[pos] = i; }
        __syncthreads();
        int n = cnt;
        float s0 = 0.f, s1 = 0.f, q0 = 0.f, q1 = 0.f, sc = 0.f;
        for (int j = 0; j < n; j++) {
            int r = list[j];
            const float* p = F + (size_t)r * D_;
            float v0 = p[t], v1 = p[t + 256];
            s0 += v0; s1 += v1; q0 += v0 * v0; q1 += v1 * v1;
        }
        for (int j = t; j < n; j += 256) sc += scores[list[j]];
        float fn = (float)n;
        float safe_n = fmaxf(fn, 1.f);
        float m0 = s0 / safe_n, m1 = s1 / safe_n;
        float dv = fmaxf(fn - 1.f, 1.f);
        float v0 = (q0 - fn * m0 * m0) / dv;
        float v1 = (q1 - fn * m1 * m1) / dv;
        float rv = v0 + v1;
#pragma unroll
        for (int o = 32; o; o >>= 1) { rv += __shfl_xor(rv, o); sc += __shfl_xor(sc, o); }
        __shared__ float wv[4], wsc[4];
        if ((t & 63) == 0) { wv[t >> 6] = rv; wsc[t >> 6] = sc; }
        __syncthreads();
        if (t == 0) {
            float var_mean = (wv[0] + wv[1] + wv[2] + wv[3]) / 512.f;
            var_mean = fminf(fmaxf(var_mean, 1e-6f), 100.f);
            float target = 1.f / (1.f + expf(-var_mean));
            float mean_s = (wsc[0] + wsc[1] + wsc[2] + wsc[3]) / safe_n;
            float d = mean_s - target;
            float bl = fminf(d * d, 2.f);
            if (fn > 1.f) { atomicAdd(&acc[2], bl); atomicAdd(&acc[3], 1.f); }
        }
    } else {
        int row = b - C_;
        __shared__ float f[D_];
        __shared__ float so[L_], sn[L_];
        float invf = inv_f[row] * 5.0f;
        const float* p = F + (size_t)row * D_;
        f[t] = p[t]; f[t + 256] = p[t + 256];
        __syncthreads();
        int wave = t >> 6, lane = t & 63;
        for (int j = wave; j < 2 * L_; j += 4) {
            int idx = (j < L_) ? j : j - L_;
            const float* P = ((j < L_) ? oldp : protos) + (size_t)lc[idx] * D_;
            float inv = (j < L_) ? inv_op[idx] : inv_np[idx];
            float s = 0.f;
            for (int e = lane; e < D_; e += 64) s += f[e] * P[e];
#pragma unroll
            for (int off = 32; off > 0; off >>= 1) s += __shfl_down(s, off);
            if (lane == 0) {
                float v = fminf(fmaxf(s * invf * inv, -10.f), 10.f);
                if (j < L_) so[idx] = v; else sn[idx] = v;
            }
        }
        __syncthreads();
        if (t == 0) {
            float mo = -1e30f, mn = -1e30f;
            for (int i = 0; i < L_; i++) { mo = fmaxf(mo, so[i]); mn = fmaxf(mn, sn[i]); }
            float eo = 0.f, en = 0.f;
            for (int i = 0; i < L_; i++) { eo += __expf(so[i] - mo); en += __expf(sn[i] - mn); }
            float lo = logf(eo), ln_ = logf(en);
            float kl = 0.f;
            for (int i = 0; i < L_; i++) {
                float olp = so[i] - mo - lo;
                float nlp = sn[i] - mn - ln_;
                kl += __expf(olp) * (olp - nlp);
            }
            atomicAdd(&acc[4], kl);
        }
    }
}

// ---------------- K_final: combine ----------------
__global__ void k_final(const float* __restrict__ acc, float* __restrict__ out) {
    float hard = acc[0] / fmaxf(acc[1], 1.f);
    float boundary = acc[2] / fmaxf(acc[3], 1.f);
    float kl = fminf(fmaxf(acc[4] / (float)B_, 0.f), 5.f);
    out[0] = hard + 0.1f * boundary + 0.2f * kl;
}

extern "C" void kernel_launch(void* const* d_in, const int* in_sizes, int n_in,
                              void* d_out, int out_size, void* d_ws, size_t ws_size,
                              hipStream_t stream) {
    const float* feat   = (const float*)d_in[0];
    const float* buf    = (const float*)d_in[1];
    const float* protos = (const float*)d_in[2];
    const float* oldp   = (const float*)d_in[3];
    const float* W      = (const float*)d_in[4];
    const float* bb     = (const float*)d_in[5];
    const int* labels   = (const int*)d_in[6];
    const int* blab     = (const int*)d_in[7];
    const int* lc       = (const int*)d_in[8];
    float* out = (float*)d_out;

    char* wsb = (char*)d_ws;
    unsigned short* keyb = (unsigned short*)wsb;                        // 32 MiB
    __hip_bfloat16* fbf  = (__hip_bfloat16*)(wsb + 33554432);           // 1 MiB
    __hip_bfloat16* bbf  = (__hip_bfloat16*)(wsb + 34603008);           // 16 MiB
    unsigned long long* maskT = (unsigned long long*)(wsb + 51380224);  // 200 KiB
    float* inv_feat = (float*)(wsb + 51380224 + 204800);
    float* inv_np   = inv_feat + B_;
    float* inv_op   = inv_np + L_;
    float* scores   = inv_op + L_;
    int*   cnt_buf  = (int*)(scores + B_);
    float* acc      = (float*)(cnt_buf + 128);

    const int P0 = B_ + M_ + 2 * L_;
    k_pre0<<<P0 + C_ + B_ / 4, 256, 0, stream>>>(feat, buf, protos, oldp, lc, blab, W, bb,
                                                 fbf, bbf, inv_feat, inv_np, inv_op,
                                                 maskT, cnt_buf, scores, acc);
    dim3 g(M_ / TN, B_ / TM);
    k_gemm<<<g, 256, 0, stream>>>(fbf, bbf, keyb);
    k_select<<<B_, 256, 0, stream>>>(keyb, labels, maskT, cnt_buf, acc);
    k_tail<<<C_ + B_, 256, 0, stream>>>(feat, labels, scores, protos, oldp, lc,
                                        inv_feat, inv_np, inv_op, acc);
    k_final<<<1, 1, 0, stream>>>(acc, out);
}

// Round 12
// 193.842 us; speedup vs baseline: 1.5686x; 1.0505x over previous
//
#include <hip/hip_runtime.h>
#include <hip/hip_bf16.h>
#include <math.h>

#define B_ 1024
#define M_ 16384
#define D_ 512
#define C_ 100
#define L_ 50

using short8  = __attribute__((ext_vector_type(8))) short;
using ushort8 = __attribute__((ext_vector_type(8))) unsigned short;
using f32x4   = __attribute__((ext_vector_type(4))) float;

__device__ inline void async16(const void* g, void* l) {
    __builtin_amdgcn_global_load_lds(
        (const __attribute__((address_space(1))) unsigned int*)g,
        (__attribute__((address_space(3))) unsigned int*)l, 16, 0, 0);
}

// ---------------- K_pre0: normalized bf16 (feat/buffer/protos) + masks + scores ----
// blocks [0,B_): fbf; [B_,B_+M_): bbf; [B_+M_,+L_): pbf rows 50+j (new protos);
// [B_+M_+L_, P0): pbf rows j (old protos); [P0,P0+C_): maskT+cnt; rest: scores.
__global__ __launch_bounds__(256) void k_pre0(
    const float* __restrict__ feat, const float* __restrict__ buf,
    const float* __restrict__ protos, const float* __restrict__ oldp,
    const int* __restrict__ lc, const int* __restrict__ blab,
    const float* __restrict__ W, const float* __restrict__ bbias,
    __hip_bfloat16* __restrict__ fbf, __hip_bfloat16* __restrict__ bbf,
    __hip_bfloat16* __restrict__ pbf,
    unsigned long long* __restrict__ maskT, int* __restrict__ cnt_buf,
    float* __restrict__ scores, float* __restrict__ acc) {
    const int P0 = B_ + M_ + 2 * L_;
    int b = blockIdx.x, t = threadIdx.x;
    if (b < P0) {
        const float* src; int row;
        __hip_bfloat16* dst;
        if (b < B_)                { src = feat;   row = b;                 dst = fbf + (size_t)b * D_; }
        else if (b < B_ + M_)      { int j = b - B_;           src = buf;    row = j;     dst = bbf + (size_t)j * D_; }
        else if (b < B_ + M_ + L_) { int j = b - B_ - M_;      src = protos; row = lc[j]; dst = pbf + (size_t)(L_ + j) * D_; }
        else                       { int j = b - B_ - M_ - L_; src = oldp;   row = lc[j]; dst = pbf + (size_t)j * D_; }
        const float* p = src + (size_t)row * D_;
        float v0 = p[t], v1 = p[t + 256];
        float ss = v0 * v0 + v1 * v1;
#pragma unroll
        for (int m = 32; m; m >>= 1) ss += __shfl_xor(ss, m);
        __shared__ float w4[4];
        if ((t & 63) == 0) w4[t >> 6] = ss;
        __syncthreads();
        float inv = 1.f / fmaxf(sqrtf(w4[0] + w4[1] + w4[2] + w4[3]), 1e-12f);
        dst[t] = __float2bfloat16(v0 * inv); dst[t + 256] = __float2bfloat16(v1 * inv);
    } else if (b < P0 + C_) {
        int c2 = b - P0;
        unsigned long long m = 0;
#pragma unroll
        for (int q = 0; q < 8; q++) {
            int base = q * 2048 + t * 8;
            int4 l0 = *(const int4*)(blab + base);
            int4 l1 = *(const int4*)(blab + base + 4);
            unsigned by = 0;
            by |= (unsigned)(l0.x == c2) << 0; by |= (unsigned)(l0.y == c2) << 1;
            by |= (unsigned)(l0.z == c2) << 2; by |= (unsigned)(l0.w == c2) << 3;
            by |= (unsigned)(l1.x == c2) << 4; by |= (unsigned)(l1.y == c2) << 5;
            by |= (unsigned)(l1.z == c2) << 6; by |= (unsigned)(l1.w == c2) << 7;
            m |= ((unsigned long long)by) << (8 * q);
        }
        maskT[(size_t)c2 * 256 + t] = m;
        int c = __popcll(m);
#pragma unroll
        for (int o = 32; o; o >>= 1) c += __shfl_xor(c, o);
        __shared__ int iw4[4];
        if ((t & 63) == 0) iw4[t >> 6] = c;
        __syncthreads();
        if (t == 0) cnt_buf[c2] = iw4[0] + iw4[1] + iw4[2] + iw4[3];
    } else {
        int bb2 = b - P0 - C_;
        if (bb2 == 0 && t < 8) acc[t] = 0.f;
        int wave = t >> 6, lane = t & 63;
        int row = bb2 * 4 + wave;
        const float* p = feat + (size_t)row * D_;
        float s = 0.f;
        for (int e = lane; e < D_; e += 64) s += p[e] * W[e];
#pragma unroll
        for (int off = 32; off > 0; off >>= 1) s += __shfl_down(s, off);
        if (lane == 0) scores[row] = 1.f / (1.f + __expf(-(s + bbias[0])));
    }
}

// ---------------- K2: bf16 MFMA GEMM -> 16-bit sort keys (clean, keys-only) ----
#define TM 128
#define TN 128
#define TK 32
#define CPITCH 136
__global__ __launch_bounds__(256) void k_gemm(
    const __hip_bfloat16* __restrict__ A, const __hip_bfloat16* __restrict__ Bm,
    unsigned short* __restrict__ keys) {
    __shared__ unsigned short smem[TM * CPITCH];
    unsigned short* As = smem;
    unsigned short* Bs = smem + TM * TK;
    int t = threadIdx.x;
    int wave = t >> 6, lane = t & 63;
    int row0 = blockIdx.y * TM;
    int col0 = blockIdx.x * TN;
    int c0 = t, c1 = t + 256;
    const ushort* Ag0 = (const ushort*)A + (size_t)(row0 + (c0 >> 2)) * D_ + (c0 & 3) * 8;
    const ushort* Ag1 = (const ushort*)A + (size_t)(row0 + (c1 >> 2)) * D_ + (c1 & 3) * 8;
    const ushort* Bg0 = (const ushort*)Bm + (size_t)(col0 + (c0 >> 2)) * D_ + (c0 & 3) * 8;
    const ushort* Bg1 = (const ushort*)Bm + (size_t)(col0 + (c1 >> 2)) * D_ + (c1 & 3) * 8;
    unsigned short* As0 = &As[c0 * 8]; unsigned short* As1 = &As[c1 * 8];
    unsigned short* Bs0 = &Bs[c0 * 8]; unsigned short* Bs1 = &Bs[c1 * 8];
    int wm = (wave & 1) * 64, wn = (wave >> 1) * 64;
    f32x4 acc[4][4];
#pragma unroll
    for (int i = 0; i < 4; i++)
#pragma unroll
        for (int j = 0; j < 4; j++) acc[i][j] = {0.f, 0.f, 0.f, 0.f};
    int fr = lane & 15, fk = (lane >> 4) * 8;
    for (int k0 = 0; k0 < D_; k0 += TK) {
        async16(Ag0 + k0, As0);
        async16(Ag1 + k0, As1);
        async16(Bg0 + k0, Bs0);
        async16(Bg1 + k0, Bs1);
        __syncthreads();
        short8 af[4], bf2[4];
#pragma unroll
        for (int i = 0; i < 4; i++)
            af[i] = *(const short8*)&As[(wm + i * 16 + fr) * TK + fk];
#pragma unroll
        for (int j = 0; j < 4; j++)
            bf2[j] = *(const short8*)&Bs[(wn + j * 16 + fr) * TK + fk];
#pragma unroll
        for (int i = 0; i < 4; i++)
#pragma unroll
            for (int j = 0; j < 4; j++)
                acc[i][j] = __builtin_amdgcn_mfma_f32_16x16x32_bf16(af[i], bf2[j], acc[i][j], 0, 0, 0);
        __syncthreads();
    }
    int quad = lane >> 4, cpos = lane & 15;
#pragma unroll
    for (int i = 0; i < 4; i++)
#pragma unroll
        for (int j = 0; j < 4; j++)
#pragma unroll
            for (int r = 0; r < 4; r++) {
                int lr2 = wm + i * 16 + quad * 4 + r;
                int lc2 = wn + j * 16 + cpos;
                float v = fminf(fmaxf(acc[i][j][r] * 5.0f, -10.f), 10.f);
                unsigned u = __float_as_uint(v);
                unsigned bits = (u + 0x7FFFu + ((u >> 16) & 1u)) >> 16;   // RNE bf16
                unsigned key = (bits & 0x8000u) ? (~bits & 0xFFFFu) : (bits | 0x8000u);
                smem[lr2 * CPITCH + lc2] = (unsigned short)key;
            }
    __syncthreads();
    int lr3 = t >> 4, lc3 = (t & 15) * 8;
#pragma unroll
    for (int p = 0; p < 8; p++) {
        int row = p * 16 + lr3;
        uint4 kv = *(const uint4*)&smem[row * CPITCH + lc3];
        *(uint4*)&keys[(size_t)(row0 + row) * M_ + col0 + lc3] = kv;
    }
}

// ---------------- K2b: PRD logits via MFMA: psims[1024][128] (cols 0-49 old, 50-99 new)
__global__ __launch_bounds__(256) void k_psims(
    const __hip_bfloat16* __restrict__ A, const __hip_bfloat16* __restrict__ P,
    float* __restrict__ psims) {
    __shared__ unsigned short As[TM * TK];
    __shared__ unsigned short Bs[TM * TK];
    int t = threadIdx.x;
    int wave = t >> 6, lane = t & 63;
    int row0 = blockIdx.x * TM;
    int c0 = t, c1 = t + 256;
    const ushort* Ag0 = (const ushort*)A + (size_t)(row0 + (c0 >> 2)) * D_ + (c0 & 3) * 8;
    const ushort* Ag1 = (const ushort*)A + (size_t)(row0 + (c1 >> 2)) * D_ + (c1 & 3) * 8;
    const ushort* Bg0 = (const ushort*)P + (size_t)(c0 >> 2) * D_ + (c0 & 3) * 8;
    const ushort* Bg1 = (const ushort*)P + (size_t)(c1 >> 2) * D_ + (c1 & 3) * 8;
    int bval0 = (c0 >> 2) < 2 * L_, bval1 = (c1 >> 2) < 2 * L_;
    // zero the never-staged B slots (proto rows 100..127) once; they stay zero
    if (!bval0) { uint4 z; z.x = z.y = z.z = z.w = 0; *(uint4*)&Bs[c0 * 8] = z; }
    if (!bval1) { uint4 z; z.x = z.y = z.z = z.w = 0; *(uint4*)&Bs[c1 * 8] = z; }
    unsigned short* As0 = &As[c0 * 8]; unsigned short* As1 = &As[c1 * 8];
    unsigned short* Bs0 = &Bs[c0 * 8]; unsigned short* Bs1 = &Bs[c1 * 8];
    int wm = (wave & 1) * 64, wn = (wave >> 1) * 64;
    f32x4 acc[4][4];
#pragma unroll
    for (int i = 0; i < 4; i++)
#pragma unroll
        for (int j = 0; j < 4; j++) acc[i][j] = {0.f, 0.f, 0.f, 0.f};
    int fr = lane & 15, fk = (lane >> 4) * 8;
    for (int k0 = 0; k0 < D_; k0 += TK) {
        async16(Ag0 + k0, As0);
        async16(Ag1 + k0, As1);
        if (bval0) async16(Bg0 + k0, Bs0);
        if (bval1) async16(Bg1 + k0, Bs1);
        __syncthreads();
        short8 af[4], bf2[4];
#pragma unroll
        for (int i = 0; i < 4; i++)
            af[i] = *(const short8*)&As[(wm + i * 16 + fr) * TK + fk];
#pragma unroll
        for (int j = 0; j < 4; j++)
            bf2[j] = *(const short8*)&Bs[(wn + j * 16 + fr) * TK + fk];
#pragma unroll
        for (int i = 0; i < 4; i++)
#pragma unroll
            for (int j = 0; j < 4; j++)
                acc[i][j] = __builtin_amdgcn_mfma_f32_16x16x32_bf16(af[i], bf2[j], acc[i][j], 0, 0, 0);
        __syncthreads();
    }
    int quad = lane >> 4, cpos = lane & 15;
#pragma unroll
    for (int i = 0; i < 4; i++)
#pragma unroll
        for (int j = 0; j < 4; j++) {
            int gc = wn + j * 16 + cpos;
            if (gc >= 2 * L_) continue;
#pragma unroll
            for (int r = 0; r < 4; r++) {
                int gr = row0 + wm + i * 16 + quad * 4 + r;
                float v = fminf(fmaxf(acc[i][j][r] * 5.0f, -10.f), 10.f);
                psims[(size_t)gr * 128 + gc] = v;
            }
        }
}

// ---------------- K3: stage->sums->saturation cert; exact bisection fallback ----
__device__ inline float keyval(unsigned key) {
    unsigned bits = (key & 0x8000u) ? (key ^ 0x8000u) : (~key & 0xFFFFu);
    return __uint_as_float(bits << 16);
}

__global__ __launch_bounds__(256) void k_select(
    const unsigned short* __restrict__ keys, const int* __restrict__ labels,
    const unsigned long long* __restrict__ maskT, const int* __restrict__ cnt_buf,
    float* __restrict__ acc) {
    __shared__ unsigned sku[8192];
    __shared__ int warr[16][4];
    __shared__ float rT[4], rP[4], rS[4]; __shared__ int rC[4];
    int row = blockIdx.x;
    int t = threadIdx.x;
    int wave = t >> 6;
    int lab = labels[row];
    unsigned long long pm = maskT[(size_t)lab * 256 + t];
    const unsigned short* kr = keys + (size_t)row * M_ + t * 8;

#pragma unroll
    for (int q = 0; q < 8; q++)
        async16(kr + q * 2048, &sku[(q * 256 + t) * 4]);
    __syncthreads();

    float tot = 0.f;
#pragma unroll
    for (int q = 0; q < 8; q++) {
        uint4 w = *(const uint4*)&sku[(unsigned)(q * 256 + t) * 4];
#define TSUM(x) tot += __expf(keyval((x) >> 16)) + __expf(keyval((x) & 0xFFFFu));
        TSUM(w.x) TSUM(w.y) TSUM(w.z) TSUM(w.w)
#undef TSUM
    }
    float pp = 0.f;
#pragma unroll
    for (int q = 0; q < 8; q++) {
        unsigned pb = (unsigned)(pm >> (8 * q)) & 0xFFu;
        while (pb) {
            int b = __ffs(pb) - 1; pb &= pb - 1;
            unsigned idx = (unsigned)(q * 256 + t) * 4 + (b >> 1);
            unsigned w = sku[idx];
            unsigned key = (b & 1) ? (w >> 16) : (w & 0xFFFFu);
            pp += __expf(keyval(key));
            sku[idx] = (b & 1) ? (w & 0x0000FFFFu) : (w & 0xFFFF0000u);
        }
    }
#pragma unroll
    for (int o = 32; o; o >>= 1) { tot += __shfl_xor(tot, o); pp += __shfl_xor(pp, o); }
    if ((t & 63) == 0) { rT[wave] = tot; rP[wave] = pp; }
    __syncthreads();
    float TOT = rT[0] + rT[1] + rT[2] + rT[3];
    float PP  = rP[0] + rP[1] + rP[2] + rP[3];

    int n_pos = cnt_buf[lab];
    int n_neg = M_ - n_pos;
    int k = (int)(0.7f * (float)n_neg);

    int skip = 0;
    if (n_pos <= 0 || k <= 0) {
        skip = 1;
    } else {
        float pos_exp = PP / (float)n_pos;
        float neg_lb = (TOT - PP) * ((float)k / (float)n_neg);   // top-k >= k*mean
        float ratio_ub = pos_exp / (pos_exp + neg_lb);
        if (ratio_ub < 6.0e-3f) {        // < e^-5, margin 25x -> loss == 5.0 exactly
            if (t == 0) { atomicAdd(&acc[0], 5.0f); atomicAdd(&acc[1], 1.0f); }
            skip = 1;
        }
    }
    if (skip) return;

    unsigned cur = 0;
    for (int r = 15; r >= 0; r--) {
        unsigned T = cur | (1u << r);
        unsigned Th = T << 16;
        int cnt = 0;
#pragma unroll
        for (int q = 0; q < 8; q++) {
            uint4 w = *(const uint4*)&sku[(unsigned)(q * 256 + t) * 4];
            cnt += __popcll(__ballot(w.x >= Th)) + __popcll(__ballot((w.x & 0xFFFFu) >= T));
            cnt += __popcll(__ballot(w.y >= Th)) + __popcll(__ballot((w.y & 0xFFFFu) >= T));
            cnt += __popcll(__ballot(w.z >= Th)) + __popcll(__ballot((w.z & 0xFFFFu) >= T));
            cnt += __popcll(__ballot(w.w >= Th)) + __popcll(__ballot((w.w & 0xFFFFu) >= T));
        }
        if ((t & 63) == 0) warr[15 - r][wave] = cnt;
        __syncthreads();
        int tot2 = warr[15 - r][0] + warr[15 - r][1] + warr[15 - r][2] + warr[15 - r][3];
        if (tot2 >= k) cur = T;
    }

    int cgt = 0; float sgt = 0.f;
#pragma unroll
    for (int q = 0; q < 8; q++) {
        uint4 w = *(const uint4*)&sku[(unsigned)(q * 256 + t) * 4];
#define HALVES(x)                                                              \
        { unsigned hk = (x) >> 16;    if (hk > cur) { cgt++; sgt += __expf(keyval(hk)); } \
          unsigned lk = (x) & 0xFFFFu; if (lk > cur) { cgt++; sgt += __expf(keyval(lk)); } }
        HALVES(w.x) HALVES(w.y) HALVES(w.z) HALVES(w.w)
#undef HALVES
    }
#pragma unroll
    for (int o = 32; o; o >>= 1) { sgt += __shfl_xor(sgt, o); cgt += __shfl_xor(cgt, o); }
    if ((t & 63) == 0) { rS[wave] = sgt; rC[wave] = cgt; }
    __syncthreads();
    if (t == 0) {
        float sumGt = rS[0] + rS[1] + rS[2] + rS[3];
        int   cntGt = rC[0] + rC[1] + rC[2] + rC[3];
        float negExp = sumGt + (float)(k - cntGt) * __expf(keyval(cur));
        float pos_exp = PP / (float)max(n_pos, 1);
        float denom = fmaxf(pos_exp + negExp, 1e-8f);
        float ratio = fminf(fmaxf(pos_exp / denom, 1e-8f), 1.0f);
        float loss = fminf(fmaxf(-logf(ratio), 0.f), 5.f);
        atomicAdd(&acc[0], loss); atomicAdd(&acc[1], 1.f);
    }
}

// ---------------- K_tail: boundary stats (compacted) + parallel KL from psims ----
// blocks [0,C_): boundary for class b; blocks [C_, C_+B_/4): KL, 1 wave = 1 row.
__global__ __launch_bounds__(256) void k_tail(
    const float* __restrict__ F, const int* __restrict__ labels,
    const float* __restrict__ scores, const float* __restrict__ psims,
    float* __restrict__ acc) {
    int b = blockIdx.x, t = threadIdx.x;
    if (b < C_) {
        int c = b;
        __shared__ int list[B_];
        __shared__ int cnt;
        if (t == 0) cnt = 0;
        __syncthreads();
        for (int i = t; i < B_; i += 256)
            if (labels[i] == c) { int pos = atomicAdd(&cnt, 1); list[pos] = i; }
        __syncthreads();
        int n = cnt;
        float s0 = 0.f, s1 = 0.f, q0 = 0.f, q1 = 0.f, sc = 0.f;
        for (int j = 0; j < n; j++) {
            int r = list[j];
            const float* p = F + (size_t)r * D_;
            float v0 = p[t], v1 = p[t + 256];
            s0 += v0; s1 += v1; q0 += v0 * v0; q1 += v1 * v1;
        }
        for (int j = t; j < n; j += 256) sc += scores[list[j]];
        float fn = (float)n;
        float safe_n = fmaxf(fn, 1.f);
        float m0 = s0 / safe_n, m1 = s1 / safe_n;
        float dv = fmaxf(fn - 1.f, 1.f);
        float v0 = (q0 - fn * m0 * m0) / dv;
        float v1 = (q1 - fn * m1 * m1) / dv;
        float rv = v0 + v1;
#pragma unroll
        for (int o = 32; o; o >>= 1) { rv += __shfl_xor(rv, o); sc += __shfl_xor(sc, o); }
        __shared__ float wv[4], wsc[4];
        if ((t & 63) == 0) { wv[t >> 6] = rv; wsc[t >> 6] = sc; }
        __syncthreads();
        if (t == 0) {
            float var_mean = (wv[0] + wv[1] + wv[2] + wv[3]) / 512.f;
            var_mean = fminf(fmaxf(var_mean, 1e-6f), 100.f);
            float target = 1.f / (1.f + expf(-var_mean));
            float mean_s = (wsc[0] + wsc[1] + wsc[2] + wsc[3]) / safe_n;
            float d = mean_s - target;
            float bl = fminf(d * d, 2.f);
            if (fn > 1.f) { atomicAdd(&acc[2], bl); atomicAdd(&acc[3], 1.f); }
        }
    } else {
        int wave = t >> 6, lane = t & 63;
        int row = (b - C_) * 4 + wave;
        const float* pr = psims + (size_t)row * 128;
        bool on = lane < L_;
        float o  = on ? pr[lane]       : -1e30f;
        float nn = on ? pr[L_ + lane]  : -1e30f;
        float mo = o, mn = nn;
#pragma unroll
        for (int s = 32; s; s >>= 1) {
            mo = fmaxf(mo, __shfl_xor(mo, s));
            mn = fmaxf(mn, __shfl_xor(mn, s));
        }
        float eo = on ? __expf(o - mo) : 0.f;
        float en = on ? __expf(nn - mn) : 0.f;
#pragma unroll
        for (int s = 32; s; s >>= 1) { eo += __shfl_xor(eo, s); en += __shfl_xor(en, s); }
        float lo = logf(eo), ln_ = logf(en);
        float olp = o - mo - lo;
        float nlp = nn - mn - ln_;
        float kl = on ? __expf(olp) * (olp - nlp) : 0.f;
#pragma unroll
        for (int s = 32; s; s >>= 1) kl += __shfl_xor(kl, s);
        if (lane == 0) atomicAdd(&acc[4], kl);
    }
}

// ---------------- K_final: combine ----------------
__global__ void k_final(const float* __restrict__ acc, float* __restrict__ out) {
    float hard = acc[0] / fmaxf(acc[1], 1.f);
    float boundary = acc[2] / fmaxf(acc[3], 1.f);
    float kl = fminf(fmaxf(acc[4] / (float)B_, 0.f), 5.f);
    out[0] = hard + 0.1f * boundary + 0.2f * kl;
}

extern "C" void kernel_launch(void* const* d_in, const int* in_sizes, int n_in,
                              void* d_out, int out_size, void* d_ws, size_t ws_size,
                              hipStream_t stream) {
    const float* feat   = (const float*)d_in[0];
    const float* buf    = (const float*)d_in[1];
    const float* protos = (const float*)d_in[2];
    const float* oldp   = (const float*)d_in[3];
    const float* W      = (const float*)d_in[4];
    const float* bb     = (const float*)d_in[5];
    const int* labels   = (const int*)d_in[6];
    const int* blab     = (const int*)d_in[7];
    const int* lc       = (const int*)d_in[8];
    float* out = (float*)d_out;

    char* wsb = (char*)d_ws;
    unsigned short* keyb = (unsigned short*)wsb;                        // 32 MiB
    __hip_bfloat16* fbf  = (__hip_bfloat16*)(wsb + 33554432);           // 1 MiB
    __hip_bfloat16* bbf  = (__hip_bfloat16*)(wsb + 34603008);           // 16 MiB
    unsigned long long* maskT = (unsigned long long*)(wsb + 51380224);  // 200 KiB
    __hip_bfloat16* pbf  = (__hip_bfloat16*)(wsb + 51585024);           // 128 KiB (100 rows used)
    float* psims = (float*)(wsb + 51716096);                            // 512 KiB
    float* scores = (float*)(wsb + 52240384);
    int*   cnt_buf = (int*)(scores + B_);
    float* acc     = (float*)(cnt_buf + 128);

    const int P0 = B_ + M_ + 2 * L_;
    k_pre0<<<P0 + C_ + B_ / 4, 256, 0, stream>>>(feat, buf, protos, oldp, lc, blab, W, bb,
                                                 fbf, bbf, pbf, maskT, cnt_buf, scores, acc);
    dim3 g(M_ / TN, B_ / TM);
    k_gemm<<<g, 256, 0, stream>>>(fbf, bbf, keyb);
    k_psims<<<B_ / TM, 256, 0, stream>>>(fbf, pbf, psims);
    k_select<<<B_, 256, 0, stream>>>(keyb, labels, maskT, cnt_buf, acc);
    k_tail<<<C_ + B_ / 4, 256, 0, stream>>>(feat, labels, scores, psims, acc);
    k_final<<<1, 1, 0, stream>>>(acc, out);
}

// Round 13
// 181.084 us; speedup vs baseline: 1.6791x; 1.0705x over previous
//
#include <hip/hip_runtime.h>
#include <hip/hip_bf16.h>
#include <math.h>

#define B_ 1024
#define M_ 16384
#define D_ 512
#define C_ 100
#define L_ 50

using short8  = __attribute__((ext_vector_type(8))) short;
using ushort8 = __attribute__((ext_vector_type(8))) unsigned short;
using f32x4   = __attribute__((ext_vector_type(4))) float;

__device__ inline void async16(const void* g, void* l) {
    __builtin_amdgcn_global_load_lds(
        (const __attribute__((address_space(1))) unsigned int*)g,
        (__attribute__((address_space(3))) unsigned int*)l, 16, 0, 0);
}

__device__ inline unsigned short f2bf(float x) {   // RNE bf16 (normal values)
    unsigned u = __float_as_uint(x);
    return (unsigned short)((u + 0x7FFFu + ((u >> 16) & 1u)) >> 16);
}

// ---------------- K_pre0: wave-per-row norms/bf16 + class bitmasks + scores ----
// norm rows: [0,B_) fbf; [B_,B_+M_) bbf; then L_ new protos (pbf rows 50+j);
// then L_ old protos (pbf rows j). 4 rows per block (1 per wave), no barriers.
#define NROWS (B_ + M_ + 2 * L_)
#define NB4   (NROWS / 4)
__global__ __launch_bounds__(256) void k_pre0(
    const float* __restrict__ feat, const float* __restrict__ buf,
    const float* __restrict__ protos, const float* __restrict__ oldp,
    const int* __restrict__ lc, const int* __restrict__ blab,
    const float* __restrict__ W, const float* __restrict__ bbias,
    __hip_bfloat16* __restrict__ fbf, __hip_bfloat16* __restrict__ bbf,
    __hip_bfloat16* __restrict__ pbf,
    unsigned long long* __restrict__ maskT, int* __restrict__ cnt_buf,
    float* __restrict__ scores, float* __restrict__ acc) {
    int b = blockIdx.x, t = threadIdx.x;
    int wave = t >> 6, lane = t & 63;
    if (b < NB4) {
        int idx = b * 4 + wave;
        const float* src; int row; __hip_bfloat16* dst;
        if (idx < B_)                { src = feat;   row = idx;               dst = fbf + (size_t)idx * D_; }
        else if (idx < B_ + M_)      { int j = idx - B_;           src = buf;    row = j;     dst = bbf + (size_t)j * D_; }
        else if (idx < B_ + M_ + L_) { int j = idx - B_ - M_;      src = protos; row = lc[j]; dst = pbf + (size_t)(L_ + j) * D_; }
        else                         { int j = idx - B_ - M_ - L_; src = oldp;   row = lc[j]; dst = pbf + (size_t)j * D_; }
        const float* p = src + (size_t)row * D_ + lane * 8;
        float4 a = *(const float4*)p;
        float4 c = *(const float4*)(p + 4);
        float ss = a.x * a.x + a.y * a.y + a.z * a.z + a.w * a.w
                 + c.x * c.x + c.y * c.y + c.z * c.z + c.w * c.w;
#pragma unroll
        for (int m = 32; m; m >>= 1) ss += __shfl_xor(ss, m);
        float inv = 1.f / fmaxf(sqrtf(ss), 1e-12f);
        ushort8 o;
        o[0] = f2bf(a.x * inv); o[1] = f2bf(a.y * inv);
        o[2] = f2bf(a.z * inv); o[3] = f2bf(a.w * inv);
        o[4] = f2bf(c.x * inv); o[5] = f2bf(c.y * inv);
        o[6] = f2bf(c.z * inv); o[7] = f2bf(c.w * inv);
        *(ushort8*)((ushort*)dst + lane * 8) = o;
    } else if (b < NB4 + C_) {
        int c2 = b - NB4;
        unsigned long long m = 0;
#pragma unroll
        for (int q = 0; q < 8; q++) {
            int base = q * 2048 + t * 8;
            int4 l0 = *(const int4*)(blab + base);
            int4 l1 = *(const int4*)(blab + base + 4);
            unsigned by = 0;
            by |= (unsigned)(l0.x == c2) << 0; by |= (unsigned)(l0.y == c2) << 1;
            by |= (unsigned)(l0.z == c2) << 2; by |= (unsigned)(l0.w == c2) << 3;
            by |= (unsigned)(l1.x == c2) << 4; by |= (unsigned)(l1.y == c2) << 5;
            by |= (unsigned)(l1.z == c2) << 6; by |= (unsigned)(l1.w == c2) << 7;
            m |= ((unsigned long long)by) << (8 * q);
        }
        maskT[(size_t)c2 * 256 + t] = m;
        int c = __popcll(m);
#pragma unroll
        for (int o = 32; o; o >>= 1) c += __shfl_xor(c, o);
        __shared__ int iw4[4];
        if ((t & 63) == 0) iw4[t >> 6] = c;
        __syncthreads();
        if (t == 0) cnt_buf[c2] = iw4[0] + iw4[1] + iw4[2] + iw4[3];
    } else {
        int bb2 = b - NB4 - C_;
        if (bb2 == 0 && t < 8) acc[t] = 0.f;
        int row = bb2 * 4 + wave;
        const float* p = feat + (size_t)row * D_;
        float s = 0.f;
        for (int e = lane; e < D_; e += 64) s += p[e] * W[e];
#pragma unroll
        for (int off = 32; off > 0; off >>= 1) s += __shfl_down(s, off);
        if (lane == 0) scores[row] = 1.f / (1.f + __expf(-(s + bbias[0])));
    }
}

// ---------------- K2: bf16 MFMA GEMM -> raw bf16 sims; col-tile 128 = PRD logits ----
#define TM 128
#define TN 128
#define TK 32
#define CPITCH 136
__global__ __launch_bounds__(256) void k_gemm(
    const __hip_bfloat16* __restrict__ A, const __hip_bfloat16* __restrict__ Bm,
    const __hip_bfloat16* __restrict__ P,
    unsigned short* __restrict__ sims, float* __restrict__ psims) {
    __shared__ unsigned short smem[TM * CPITCH];
    unsigned short* As = smem;
    unsigned short* Bs = smem + TM * TK;
    int t = threadIdx.x;
    int wave = t >> 6, lane = t & 63;
    int row0 = blockIdx.y * TM;
    int wm = (wave & 1) * 64, wn = (wave >> 1) * 64;
    int fr = lane & 15, fk = (lane >> 4) * 8;
    int quad = lane >> 4, cpos = lane & 15;
    f32x4 acc[4][4];
#pragma unroll
    for (int i = 0; i < 4; i++)
#pragma unroll
        for (int j = 0; j < 4; j++) acc[i][j] = {0.f, 0.f, 0.f, 0.f};
    int c0 = t, c1 = t + 256;

    if (blockIdx.x < 128) {
        int col0 = blockIdx.x * TN;
        const ushort* Ag0 = (const ushort*)A + (size_t)(row0 + (c0 >> 2)) * D_ + (c0 & 3) * 8;
        const ushort* Ag1 = (const ushort*)A + (size_t)(row0 + (c1 >> 2)) * D_ + (c1 & 3) * 8;
        const ushort* Bg0 = (const ushort*)Bm + (size_t)(col0 + (c0 >> 2)) * D_ + (c0 & 3) * 8;
        const ushort* Bg1 = (const ushort*)Bm + (size_t)(col0 + (c1 >> 2)) * D_ + (c1 & 3) * 8;
        unsigned short* As0 = &As[c0 * 8]; unsigned short* As1 = &As[c1 * 8];
        unsigned short* Bs0 = &Bs[c0 * 8]; unsigned short* Bs1 = &Bs[c1 * 8];
        for (int k0 = 0; k0 < D_; k0 += TK) {
            async16(Ag0 + k0, As0);
            async16(Ag1 + k0, As1);
            async16(Bg0 + k0, Bs0);
            async16(Bg1 + k0, Bs1);
            __syncthreads();
            short8 af[4], bf2[4];
#pragma unroll
            for (int i = 0; i < 4; i++)
                af[i] = *(const short8*)&As[(wm + i * 16 + fr) * TK + fk];
#pragma unroll
            for (int j = 0; j < 4; j++)
                bf2[j] = *(const short8*)&Bs[(wn + j * 16 + fr) * TK + fk];
#pragma unroll
            for (int i = 0; i < 4; i++)
#pragma unroll
                for (int j = 0; j < 4; j++)
                    acc[i][j] = __builtin_amdgcn_mfma_f32_16x16x32_bf16(af[i], bf2[j], acc[i][j], 0, 0, 0);
            __syncthreads();
        }
        // epilogue: clip -> RNE bf16 bits -> LDS transpose -> dwordx4 stores
#pragma unroll
        for (int i = 0; i < 4; i++)
#pragma unroll
            for (int j = 0; j < 4; j++)
#pragma unroll
                for (int r = 0; r < 4; r++) {
                    int lr2 = wm + i * 16 + quad * 4 + r;
                    int lc2 = wn + j * 16 + cpos;
                    float v = fminf(fmaxf(acc[i][j][r] * 5.0f, -10.f), 10.f);
                    smem[lr2 * CPITCH + lc2] = f2bf(v);
                }
        __syncthreads();
        int lr3 = t >> 4, lc3 = (t & 15) * 8;
#pragma unroll
        for (int p = 0; p < 8; p++) {
            int row = p * 16 + lr3;
            uint4 kv = *(const uint4*)&smem[row * CPITCH + lc3];
            *(uint4*)&sims[(size_t)(row0 + row) * M_ + col0 + lc3] = kv;
        }
    } else {
        // PRD logits: psims[row][0..49]=old, [50..99]=new (B rows >=100 zeroed)
        const ushort* Ag0 = (const ushort*)A + (size_t)(row0 + (c0 >> 2)) * D_ + (c0 & 3) * 8;
        const ushort* Ag1 = (const ushort*)A + (size_t)(row0 + (c1 >> 2)) * D_ + (c1 & 3) * 8;
        const ushort* Bg0 = (const ushort*)P + (size_t)(c0 >> 2) * D_ + (c0 & 3) * 8;
        const ushort* Bg1 = (const ushort*)P + (size_t)(c1 >> 2) * D_ + (c1 & 3) * 8;
        int bval0 = (c0 >> 2) < 2 * L_, bval1 = (c1 >> 2) < 2 * L_;
        if (!bval0) { uint4 z; z.x = z.y = z.z = z.w = 0; *(uint4*)&Bs[c0 * 8] = z; }
        if (!bval1) { uint4 z; z.x = z.y = z.z = z.w = 0; *(uint4*)&Bs[c1 * 8] = z; }
        unsigned short* As0 = &As[c0 * 8]; unsigned short* As1 = &As[c1 * 8];
        unsigned short* Bs0 = &Bs[c0 * 8]; unsigned short* Bs1 = &Bs[c1 * 8];
        for (int k0 = 0; k0 < D_; k0 += TK) {
            async16(Ag0 + k0, As0);
            async16(Ag1 + k0, As1);
            if (bval0) async16(Bg0 + k0, Bs0);
            if (bval1) async16(Bg1 + k0, Bs1);
            __syncthreads();
            short8 af[4], bf2[4];
#pragma unroll
            for (int i = 0; i < 4; i++)
                af[i] = *(const short8*)&As[(wm + i * 16 + fr) * TK + fk];
#pragma unroll
            for (int j = 0; j < 4; j++)
                bf2[j] = *(const short8*)&Bs[(wn + j * 16 + fr) * TK + fk];
#pragma unroll
            for (int i = 0; i < 4; i++)
#pragma unroll
                for (int j = 0; j < 4; j++)
                    acc[i][j] = __builtin_amdgcn_mfma_f32_16x16x32_bf16(af[i], bf2[j], acc[i][j], 0, 0, 0);
            __syncthreads();
        }
#pragma unroll
        for (int i = 0; i < 4; i++)
#pragma unroll
            for (int j = 0; j < 4; j++) {
                int gc = wn + j * 16 + cpos;
                if (gc >= 2 * L_) continue;
#pragma unroll
                for (int r = 0; r < 4; r++) {
                    int gr = row0 + wm + i * 16 + quad * 4 + r;
                    float v = fminf(fmaxf(acc[i][j][r] * 5.0f, -10.f), 10.f);
                    psims[(size_t)gr * 128 + gc] = v;
                }
            }
    }
}

// ---------------- K3: select (cert fast path + bisection fallback) + boundary + KL ----
__device__ inline float bf2f(unsigned bits) { return __uint_as_float(bits << 16); }
__device__ inline unsigned keytx(unsigned bits) {
    return (bits & 0x8000u) ? (~bits & 0xFFFFu) : (bits | 0x8000u);
}
__device__ inline float keyval(unsigned key) {
    unsigned bits = (key & 0x8000u) ? (key ^ 0x8000u) : (~key & 0xFFFFu);
    return __uint_as_float(bits << 16);
}

__global__ __launch_bounds__(256) void k_sel_tail(
    const unsigned short* __restrict__ sims, const int* __restrict__ labels,
    const unsigned long long* __restrict__ maskT, const int* __restrict__ cnt_buf,
    const float* __restrict__ F, const float* __restrict__ scores,
    const float* __restrict__ psims, float* __restrict__ acc) {
    __shared__ unsigned sku[8192];          // select fallback keys / boundary row-list
    __shared__ int warr[16][4];
    __shared__ float r0[4], r1[4]; __shared__ int rC[4];
    int b = blockIdx.x, t = threadIdx.x;
    int wave = t >> 6, lane = t & 63;

    if (b < B_) {
        // ---------- hard-negative select ----------
        int row = b;
        int lab = labels[row];
        unsigned long long pm = maskT[(size_t)lab * 256 + t];
        const unsigned short* kr = sims + (size_t)row * M_ + t * 8;
        float tot = 0.f, pp = 0.f;
#pragma unroll
        for (int q = 0; q < 8; q++) {
            uint4 w = *(const uint4*)(kr + q * 2048);
            tot += __expf(bf2f(w.x & 0xFFFFu)) + __expf(bf2f(w.x >> 16))
                 + __expf(bf2f(w.y & 0xFFFFu)) + __expf(bf2f(w.y >> 16))
                 + __expf(bf2f(w.z & 0xFFFFu)) + __expf(bf2f(w.z >> 16))
                 + __expf(bf2f(w.w & 0xFFFFu)) + __expf(bf2f(w.w >> 16));
            unsigned pb = (unsigned)(pm >> (8 * q)) & 0xFFu;
            if (pb) {
                if (pb & 1u)   pp += __expf(bf2f(w.x & 0xFFFFu));
                if (pb & 2u)   pp += __expf(bf2f(w.x >> 16));
                if (pb & 4u)   pp += __expf(bf2f(w.y & 0xFFFFu));
                if (pb & 8u)   pp += __expf(bf2f(w.y >> 16));
                if (pb & 16u)  pp += __expf(bf2f(w.z & 0xFFFFu));
                if (pb & 32u)  pp += __expf(bf2f(w.z >> 16));
                if (pb & 64u)  pp += __expf(bf2f(w.w & 0xFFFFu));
                if (pb & 128u) pp += __expf(bf2f(w.w >> 16));
            }
        }
#pragma unroll
        for (int o = 32; o; o >>= 1) { tot += __shfl_xor(tot, o); pp += __shfl_xor(pp, o); }
        if ((t & 63) == 0) { r0[wave] = tot; r1[wave] = pp; }
        __syncthreads();
        float TOT = r0[0] + r0[1] + r0[2] + r0[3];
        float PP  = r1[0] + r1[1] + r1[2] + r1[3];

        int n_pos = cnt_buf[lab];
        int n_neg = M_ - n_pos;
        int k = (int)(0.7f * (float)n_neg);   // fp32-mul + trunc matches reference

        if (n_pos <= 0 || k <= 0) return;     // valid=0 row
        {
            float pos_exp = PP / (float)n_pos;
            float neg_lb = (TOT - PP) * ((float)k / (float)n_neg);  // top-k >= k*mean
            float ratio_ub = pos_exp / (pos_exp + neg_lb);
            if (ratio_ub < 6.0e-3f) {         // < e^-5 (6.7379e-3), 11% margin -> loss==5.0
                if (t == 0) { atomicAdd(&acc[0], 5.0f); atomicAdd(&acc[1], 1.0f); }
                return;
            }
        }

        // ---------- exact fallback: stage -> key-transform -> 16-round bisection ----
#pragma unroll
        for (int q = 0; q < 8; q++)
            async16(kr + q * 2048, &sku[(q * 256 + t) * 4]);
        __syncthreads();
#pragma unroll
        for (int q = 0; q < 8; q++) {
            unsigned pb = (unsigned)(pm >> (8 * q)) & 0xFFu;
            unsigned base = (unsigned)(q * 256 + t) * 4;
#pragma unroll
            for (int h = 0; h < 4; h++) {
                unsigned w = sku[base + h];
                unsigned lo = w & 0xFFFFu, hi = w >> 16;
                lo = (pb & (1u << (2 * h)))     ? 0u : keytx(lo);
                hi = (pb & (1u << (2 * h + 1))) ? 0u : keytx(hi);
                sku[base + h] = lo | (hi << 16);
            }
        }
        unsigned cur = 0;
        for (int r = 15; r >= 0; r--) {
            unsigned T = cur | (1u << r);
            unsigned Th = T << 16;
            int cnt = 0;
#pragma unroll
            for (int q = 0; q < 8; q++) {
                uint4 w = *(const uint4*)&sku[(unsigned)(q * 256 + t) * 4];
                cnt += __popcll(__ballot(w.x >= Th)) + __popcll(__ballot((w.x & 0xFFFFu) >= T));
                cnt += __popcll(__ballot(w.y >= Th)) + __popcll(__ballot((w.y & 0xFFFFu) >= T));
                cnt += __popcll(__ballot(w.z >= Th)) + __popcll(__ballot((w.z & 0xFFFFu) >= T));
                cnt += __popcll(__ballot(w.w >= Th)) + __popcll(__ballot((w.w & 0xFFFFu) >= T));
            }
            if ((t & 63) == 0) warr[15 - r][wave] = cnt;
            __syncthreads();
            int tt = warr[15 - r][0] + warr[15 - r][1] + warr[15 - r][2] + warr[15 - r][3];
            if (tt >= k) cur = T;
        }
        int cgt = 0; float sgt = 0.f;
#pragma unroll
        for (int q = 0; q < 8; q++) {
            uint4 w = *(const uint4*)&sku[(unsigned)(q * 256 + t) * 4];
#define HALVES(x)                                                              \
            { unsigned hk = (x) >> 16;     if (hk > cur) { cgt++; sgt += __expf(keyval(hk)); } \
              unsigned lk = (x) & 0xFFFFu; if (lk > cur) { cgt++; sgt += __expf(keyval(lk)); } }
            HALVES(w.x) HALVES(w.y) HALVES(w.z) HALVES(w.w)
#undef HALVES
        }
#pragma unroll
        for (int o = 32; o; o >>= 1) { sgt += __shfl_xor(sgt, o); cgt += __shfl_xor(cgt, o); }
        if ((t & 63) == 0) { r0[wave] = sgt; rC[wave] = cgt; }
        __syncthreads();
        if (t == 0) {
            float sumGt = r0[0] + r0[1] + r0[2] + r0[3];
            int   cntGt = rC[0] + rC[1] + rC[2] + rC[3];
            float negExp = sumGt + (float)(k - cntGt) * __expf(keyval(cur));
            float pos_exp = PP / (float)max(n_pos, 1);
            float denom = fmaxf(pos_exp + negExp, 1e-8f);
            float ratio = fminf(fmaxf(pos_exp / denom, 1e-8f), 1.0f);
            float loss = fminf(fmaxf(-logf(ratio), 0.f), 5.f);
            atomicAdd(&acc[0], loss); atomicAdd(&acc[1], 1.f);
        }
    } else if (b < B_ + C_) {
        // ---------- boundary stats for class c (compacted row list) ----------
        int c = b - B_;
        int* list = (int*)sku;
        __shared__ int bcnt;
        if (t == 0) bcnt = 0;
        __syncthreads();
        for (int i = t; i < B_; i += 256)
            if (labels[i] == c) { int pos = atomicAdd(&bcnt, 1); list[pos] = i; }
        __syncthreads();
        int n = bcnt;
        float s0 = 0.f, s1 = 0.f, q0 = 0.f, q1 = 0.f, sc = 0.f;
        for (int j = 0; j < n; j++) {
            int r = list[j];
            const float* p = F + (size_t)r * D_;
            float v0 = p[t], v1 = p[t + 256];
            s0 += v0; s1 += v1; q0 += v0 * v0; q1 += v1 * v1;
        }
        for (int j = t; j < n; j += 256) sc += scores[list[j]];
        float fn = (float)n;
        float safe_n = fmaxf(fn, 1.f);
        float m0 = s0 / safe_n, m1 = s1 / safe_n;
        float dv = fmaxf(fn - 1.f, 1.f);
        float v0 = (q0 - fn * m0 * m0) / dv;
        float v1 = (q1 - fn * m1 * m1) / dv;
        float rv = v0 + v1;
#pragma unroll
        for (int o = 32; o; o >>= 1) { rv += __shfl_xor(rv, o); sc += __shfl_xor(sc, o); }
        if ((t & 63) == 0) { r0[wave] = rv; r1[wave] = sc; }
        __syncthreads();
        if (t == 0) {
            float var_mean = (r0[0] + r0[1] + r0[2] + r0[3]) / 512.f;
            var_mean = fminf(fmaxf(var_mean, 1e-6f), 100.f);
            float target = 1.f / (1.f + expf(-var_mean));
            float mean_s = (r1[0] + r1[1] + r1[2] + r1[3]) / safe_n;
            float d = mean_s - target;
            float bl = fminf(d * d, 2.f);
            if (fn > 1.f) { atomicAdd(&acc[2], bl); atomicAdd(&acc[3], 1.f); }
        }
    } else {
        // ---------- PRD KL: one wave per feature row ----------
        int row = (b - B_ - C_) * 4 + wave;
        const float* pr = psims + (size_t)row * 128;
        bool on = lane < L_;
        float o  = on ? pr[lane]      : -1e30f;
        float nn = on ? pr[L_ + lane] : -1e30f;
        float mo = o, mn = nn;
#pragma unroll
        for (int s = 32; s; s >>= 1) {
            mo = fmaxf(mo, __shfl_xor(mo, s));
            mn = fmaxf(mn, __shfl_xor(mn, s));
        }
        float eo = on ? __expf(o - mo) : 0.f;
        float en = on ? __expf(nn - mn) : 0.f;
#pragma unroll
        for (int s = 32; s; s >>= 1) { eo += __shfl_xor(eo, s); en += __shfl_xor(en, s); }
        float lo = logf(eo), ln_ = logf(en);
        float olp = o - mo - lo;
        float nlp = nn - mn - ln_;
        float kl = on ? __expf(olp) * (olp - nlp) : 0.f;
#pragma unroll
        for (int s = 32; s; s >>= 1) kl += __shfl_xor(kl, s);
        if (lane == 0) atomicAdd(&acc[4], kl);
    }
}

// ---------------- K_final: combine ----------------
__global__ void k_final(const float* __restrict__ acc, float* __restrict__ out) {
    float hard = acc[0] / fmaxf(acc[1], 1.f);
    float boundary = acc[2] / fmaxf(acc[3], 1.f);
    float kl = fminf(fmaxf(acc[4] / (float)B_, 0.f), 5.f);
    out[0] = hard + 0.1f * boundary + 0.2f * kl;
}

extern "C" void kernel_launch(void* const* d_in, const int* in_sizes, int n_in,
                              void* d_out, int out_size, void* d_ws, size_t ws_size,
                              hipStream_t stream) {
    const float* feat   = (const float*)d_in[0];
    const float* buf    = (const float*)d_in[1];
    const float* protos = (const float*)d_in[2];
    const float* oldp   = (const float*)d_in[3];
    const float* W      = (const float*)d_in[4];
    const float* bb     = (const float*)d_in[5];
    const int* labels   = (const int*)d_in[6];
    const int* blab     = (const int*)d_in[7];
    const int* lc       = (const int*)d_in[8];
    float* out = (float*)d_out;

    char* wsb = (char*)d_ws;
    unsigned short* simb = (unsigned short*)wsb;                        // 32 MiB
    __hip_bfloat16* fbf  = (__hip_bfloat16*)(wsb + 33554432);           // 1 MiB
    __hip_bfloat16* bbf  = (__hip_bfloat16*)(wsb + 34603008);           // 16 MiB
    unsigned long long* maskT = (unsigned long long*)(wsb + 51380224);  // 200 KiB
    __hip_bfloat16* pbf  = (__hip_bfloat16*)(wsb + 51585024);           // 128 KiB
    float* psims = (float*)(wsb + 51716096);                            // 512 KiB
    float* scores = (float*)(wsb + 52240384);
    int*   cnt_buf = (int*)(scores + B_);
    float* acc     = (float*)(cnt_buf + 128);

    k_pre0<<<NB4 + C_ + B_ / 4, 256, 0, stream>>>(feat, buf, protos, oldp, lc, blab, W, bb,
                                                  fbf, bbf, pbf, maskT, cnt_buf, scores, acc);
    dim3 g(129, B_ / TM);
    k_gemm<<<g, 256, 0, stream>>>(fbf, bbf, pbf, simb, psims);
    k_sel_tail<<<B_ + C_ + B_ / 4, 256, 0, stream>>>(simb, labels, maskT, cnt_buf,
                                                     feat, scores, psims, acc);
    k_final<<<1, 1, 0, stream>>>(acc, out);
}

// Round 14
// 144.199 us; speedup vs baseline: 2.1086x; 1.2558x over previous
//
#include <hip/hip_runtime.h>
#include <hip/hip_bf16.h>
#include <math.h>

#define B_ 1024
#define M_ 16384
#define D_ 512
#define C_ 100
#define L_ 50

using short8  = __attribute__((ext_vector_type(8))) short;
using ushort8 = __attribute__((ext_vector_type(8))) unsigned short;
using f32x4   = __attribute__((ext_vector_type(4))) float;

__device__ inline void async16(const void* g, void* l) {
    __builtin_amdgcn_global_load_lds(
        (const __attribute__((address_space(1))) unsigned int*)g,
        (__attribute__((address_space(3))) unsigned int*)l, 16, 0, 0);
}

__device__ inline unsigned short f2bf(float x) {   // RNE bf16 (normal values)
    unsigned u = __float_as_uint(x);
    return (unsigned short)((u + 0x7FFFu + ((u >> 16) & 1u)) >> 16);
}
__device__ inline float bf2f(unsigned bits) { return __uint_as_float(bits << 16); }
__device__ inline unsigned keytx(unsigned bits) {
    return (bits & 0x8000u) ? (~bits & 0xFFFFu) : (bits | 0x8000u);
}
__device__ inline float keyval(unsigned key) {
    unsigned bits = (key & 0x8000u) ? (key ^ 0x8000u) : (~key & 0xFFFFu);
    return __uint_as_float(bits << 16);
}

// ---------------- K_pre0: wave-per-row norms/bf16 + class bitmasks + scores ----
#define NROWS (B_ + M_ + 2 * L_)
#define NB4   (NROWS / 4)
__global__ __launch_bounds__(256) void k_pre0(
    const float* __restrict__ feat, const float* __restrict__ buf,
    const float* __restrict__ protos, const float* __restrict__ oldp,
    const int* __restrict__ lc, const int* __restrict__ blab,
    const float* __restrict__ W, const float* __restrict__ bbias,
    __hip_bfloat16* __restrict__ fbf, __hip_bfloat16* __restrict__ bbf,
    __hip_bfloat16* __restrict__ pbf,
    unsigned long long* __restrict__ maskT, int* __restrict__ cnt_buf,
    float* __restrict__ scores) {
    int b = blockIdx.x, t = threadIdx.x;
    int wave = t >> 6, lane = t & 63;
    if (b < NB4) {
        int idx = b * 4 + wave;
        const float* src; int row; __hip_bfloat16* dst;
        if (idx < B_)                { src = feat;   row = idx;               dst = fbf + (size_t)idx * D_; }
        else if (idx < B_ + M_)      { int j = idx - B_;           src = buf;    row = j;     dst = bbf + (size_t)j * D_; }
        else if (idx < B_ + M_ + L_) { int j = idx - B_ - M_;      src = protos; row = lc[j]; dst = pbf + (size_t)(L_ + j) * D_; }
        else                         { int j = idx - B_ - M_ - L_; src = oldp;   row = lc[j]; dst = pbf + (size_t)j * D_; }
        const float* p = src + (size_t)row * D_ + lane * 8;
        float4 a = *(const float4*)p;
        float4 c = *(const float4*)(p + 4);
        float ss = a.x * a.x + a.y * a.y + a.z * a.z + a.w * a.w
                 + c.x * c.x + c.y * c.y + c.z * c.z + c.w * c.w;
#pragma unroll
        for (int m = 32; m; m >>= 1) ss += __shfl_xor(ss, m);
        float inv = 1.f / fmaxf(sqrtf(ss), 1e-12f);
        ushort8 o;
        o[0] = f2bf(a.x * inv); o[1] = f2bf(a.y * inv);
        o[2] = f2bf(a.z * inv); o[3] = f2bf(a.w * inv);
        o[4] = f2bf(c.x * inv); o[5] = f2bf(c.y * inv);
        o[6] = f2bf(c.z * inv); o[7] = f2bf(c.w * inv);
        *(ushort8*)((ushort*)dst + lane * 8) = o;
    } else if (b < NB4 + C_) {
        int c2 = b - NB4;
        unsigned long long m = 0;
#pragma unroll
        for (int q = 0; q < 8; q++) {
            int base = q * 2048 + t * 8;
            int4 l0 = *(const int4*)(blab + base);
            int4 l1 = *(const int4*)(blab + base + 4);
            unsigned by = 0;
            by |= (unsigned)(l0.x == c2) << 0; by |= (unsigned)(l0.y == c2) << 1;
            by |= (unsigned)(l0.z == c2) << 2; by |= (unsigned)(l0.w == c2) << 3;
            by |= (unsigned)(l1.x == c2) << 4; by |= (unsigned)(l1.y == c2) << 5;
            by |= (unsigned)(l1.z == c2) << 6; by |= (unsigned)(l1.w == c2) << 7;
            m |= ((unsigned long long)by) << (8 * q);
        }
        maskT[(size_t)c2 * 256 + t] = m;
        int c = __popcll(m);
#pragma unroll
        for (int o = 32; o; o >>= 1) c += __shfl_xor(c, o);
        __shared__ int iw4[4];
        if ((t & 63) == 0) iw4[t >> 6] = c;
        __syncthreads();
        if (t == 0) cnt_buf[c2] = iw4[0] + iw4[1] + iw4[2] + iw4[3];
    } else {
        int bb2 = b - NB4 - C_;
        int row = bb2 * 4 + wave;
        const float* p = feat + (size_t)row * D_;
        float s = 0.f;
        for (int e = lane; e < D_; e += 64) s += p[e] * W[e];
#pragma unroll
        for (int off = 32; off > 0; off >>= 1) s += __shfl_down(s, off);
        if (lane == 0) scores[row] = 1.f / (1.f + __expf(-(s + bbias[0])));
    }
}

// ---------------- K2: bf16 MFMA GEMM -> raw bf16 sims; col-tile 128 = PRD logits ----
#define TM 128
#define TN 128
#define TK 32
#define CPITCH 136
__global__ __launch_bounds__(256) void k_gemm(
    const __hip_bfloat16* __restrict__ A, const __hip_bfloat16* __restrict__ Bm,
    const __hip_bfloat16* __restrict__ P,
    unsigned short* __restrict__ sims, float* __restrict__ psims) {
    __shared__ unsigned short smem[TM * CPITCH];
    unsigned short* As = smem;
    unsigned short* Bs = smem + TM * TK;
    int t = threadIdx.x;
    int wave = t >> 6, lane = t & 63;
    int row0 = blockIdx.y * TM;
    int wm = (wave & 1) * 64, wn = (wave >> 1) * 64;
    int fr = lane & 15, fk = (lane >> 4) * 8;
    int quad = lane >> 4, cpos = lane & 15;
    f32x4 acc[4][4];
#pragma unroll
    for (int i = 0; i < 4; i++)
#pragma unroll
        for (int j = 0; j < 4; j++) acc[i][j] = {0.f, 0.f, 0.f, 0.f};
    int c0 = t, c1 = t + 256;

    if (blockIdx.x < 128) {
        int col0 = blockIdx.x * TN;
        const ushort* Ag0 = (const ushort*)A + (size_t)(row0 + (c0 >> 2)) * D_ + (c0 & 3) * 8;
        const ushort* Ag1 = (const ushort*)A + (size_t)(row0 + (c1 >> 2)) * D_ + (c1 & 3) * 8;
        const ushort* Bg0 = (const ushort*)Bm + (size_t)(col0 + (c0 >> 2)) * D_ + (c0 & 3) * 8;
        const ushort* Bg1 = (const ushort*)Bm + (size_t)(col0 + (c1 >> 2)) * D_ + (c1 & 3) * 8;
        unsigned short* As0 = &As[c0 * 8]; unsigned short* As1 = &As[c1 * 8];
        unsigned short* Bs0 = &Bs[c0 * 8]; unsigned short* Bs1 = &Bs[c1 * 8];
        for (int k0 = 0; k0 < D_; k0 += TK) {
            async16(Ag0 + k0, As0);
            async16(Ag1 + k0, As1);
            async16(Bg0 + k0, Bs0);
            async16(Bg1 + k0, Bs1);
            __syncthreads();
            short8 af[4], bf2[4];
#pragma unroll
            for (int i = 0; i < 4; i++)
                af[i] = *(const short8*)&As[(wm + i * 16 + fr) * TK + fk];
#pragma unroll
            for (int j = 0; j < 4; j++)
                bf2[j] = *(const short8*)&Bs[(wn + j * 16 + fr) * TK + fk];
#pragma unroll
            for (int i = 0; i < 4; i++)
#pragma unroll
                for (int j = 0; j < 4; j++)
                    acc[i][j] = __builtin_amdgcn_mfma_f32_16x16x32_bf16(af[i], bf2[j], acc[i][j], 0, 0, 0);
            __syncthreads();
        }
#pragma unroll
        for (int i = 0; i < 4; i++)
#pragma unroll
            for (int j = 0; j < 4; j++)
#pragma unroll
                for (int r = 0; r < 4; r++) {
                    int lr2 = wm + i * 16 + quad * 4 + r;
                    int lc2 = wn + j * 16 + cpos;
                    float v = fminf(fmaxf(acc[i][j][r] * 5.0f, -10.f), 10.f);
                    smem[lr2 * CPITCH + lc2] = f2bf(v);
                }
        __syncthreads();
        int lr3 = t >> 4, lc3 = (t & 15) * 8;
#pragma unroll
        for (int p = 0; p < 8; p++) {
            int row = p * 16 + lr3;
            uint4 kv = *(const uint4*)&smem[row * CPITCH + lc3];
            *(uint4*)&sims[(size_t)(row0 + row) * M_ + col0 + lc3] = kv;
        }
    } else {
        const ushort* Ag0 = (const ushort*)A + (size_t)(row0 + (c0 >> 2)) * D_ + (c0 & 3) * 8;
        const ushort* Ag1 = (const ushort*)A + (size_t)(row0 + (c1 >> 2)) * D_ + (c1 & 3) * 8;
        const ushort* Bg0 = (const ushort*)P + (size_t)(c0 >> 2) * D_ + (c0 & 3) * 8;
        const ushort* Bg1 = (const ushort*)P + (size_t)(c1 >> 2) * D_ + (c1 & 3) * 8;
        int bval0 = (c0 >> 2) < 2 * L_, bval1 = (c1 >> 2) < 2 * L_;
        if (!bval0) { uint4 z; z.x = z.y = z.z = z.w = 0; *(uint4*)&Bs[c0 * 8] = z; }
        if (!bval1) { uint4 z; z.x = z.y = z.z = z.w = 0; *(uint4*)&Bs[c1 * 8] = z; }
        unsigned short* As0 = &As[c0 * 8]; unsigned short* As1 = &As[c1 * 8];
        unsigned short* Bs0 = &Bs[c0 * 8]; unsigned short* Bs1 = &Bs[c1 * 8];
        for (int k0 = 0; k0 < D_; k0 += TK) {
            async16(Ag0 + k0, As0);
            async16(Ag1 + k0, As1);
            if (bval0) async16(Bg0 + k0, Bs0);
            if (bval1) async16(Bg1 + k0, Bs1);
            __syncthreads();
            short8 af[4], bf2[4];
#pragma unroll
            for (int i = 0; i < 4; i++)
                af[i] = *(const short8*)&As[(wm + i * 16 + fr) * TK + fk];
#pragma unroll
            for (int j = 0; j < 4; j++)
                bf2[j] = *(const short8*)&Bs[(wn + j * 16 + fr) * TK + fk];
#pragma unroll
            for (int i = 0; i < 4; i++)
#pragma unroll
                for (int j = 0; j < 4; j++)
                    acc[i][j] = __builtin_amdgcn_mfma_f32_16x16x32_bf16(af[i], bf2[j], acc[i][j], 0, 0, 0);
            __syncthreads();
        }
#pragma unroll
        for (int i = 0; i < 4; i++)
#pragma unroll
            for (int j = 0; j < 4; j++) {
                int gc = wn + j * 16 + cpos;
                if (gc >= 2 * L_) continue;
#pragma unroll
                for (int r = 0; r < 4; r++) {
                    int gr = row0 + wm + i * 16 + quad * 4 + r;
                    float v = fminf(fmaxf(acc[i][j][r] * 5.0f, -10.f), 10.f);
                    psims[(size_t)gr * 128 + gc] = v;
                }
            }
    }
}

// ---------------- K3: cert + boundary + KL — slot writes, ZERO contended atomics ----
// hardLoss[row]: 5.0 certified | -1 invalid | -2 needs exact fallback (k_final)
__global__ __launch_bounds__(256) void k_cert_tail(
    const unsigned short* __restrict__ sims, const int* __restrict__ labels,
    const unsigned long long* __restrict__ maskT, const int* __restrict__ cnt_buf,
    const float* __restrict__ F, const float* __restrict__ scores,
    const float* __restrict__ psims,
    float* __restrict__ hardLoss, float* __restrict__ posP,
    float* __restrict__ blSlot, float* __restrict__ klrow) {
    __shared__ float r0[4], r1[4];
    __shared__ int list[B_];
    __shared__ int bcnt;
    int b = blockIdx.x, t = threadIdx.x;
    int wave = t >> 6, lane = t & 63;

    if (b < B_) {
        int row = b;
        int lab = labels[row];
        unsigned long long pm = maskT[(size_t)lab * 256 + t];
        const unsigned short* kr = sims + (size_t)row * M_ + t * 8;
        float tot = 0.f, pp = 0.f;
#pragma unroll
        for (int q = 0; q < 8; q++) {
            uint4 w = *(const uint4*)(kr + q * 2048);
            tot += __expf(bf2f(w.x & 0xFFFFu)) + __expf(bf2f(w.x >> 16))
                 + __expf(bf2f(w.y & 0xFFFFu)) + __expf(bf2f(w.y >> 16))
                 + __expf(bf2f(w.z & 0xFFFFu)) + __expf(bf2f(w.z >> 16))
                 + __expf(bf2f(w.w & 0xFFFFu)) + __expf(bf2f(w.w >> 16));
            unsigned pb = (unsigned)(pm >> (8 * q)) & 0xFFu;
            if (pb) {
                if (pb & 1u)   pp += __expf(bf2f(w.x & 0xFFFFu));
                if (pb & 2u)   pp += __expf(bf2f(w.x >> 16));
                if (pb & 4u)   pp += __expf(bf2f(w.y & 0xFFFFu));
                if (pb & 8u)   pp += __expf(bf2f(w.y >> 16));
                if (pb & 16u)  pp += __expf(bf2f(w.z & 0xFFFFu));
                if (pb & 32u)  pp += __expf(bf2f(w.z >> 16));
                if (pb & 64u)  pp += __expf(bf2f(w.w & 0xFFFFu));
                if (pb & 128u) pp += __expf(bf2f(w.w >> 16));
            }
        }
#pragma unroll
        for (int o = 32; o; o >>= 1) { tot += __shfl_xor(tot, o); pp += __shfl_xor(pp, o); }
        if ((t & 63) == 0) { r0[wave] = tot; r1[wave] = pp; }
        __syncthreads();
        if (t == 0) {
            float TOT = r0[0] + r0[1] + r0[2] + r0[3];
            float PP  = r1[0] + r1[1] + r1[2] + r1[3];
            posP[row] = PP;
            int n_pos = cnt_buf[lab];
            int n_neg = M_ - n_pos;
            int k = (int)(0.7f * (float)n_neg);   // fp32-mul + trunc matches reference
            float verdict;
            if (n_pos <= 0 || k <= 0) {
                verdict = -1.f;                    // invalid row
            } else {
                float pos_exp = PP / (float)n_pos;
                float neg_lb = (TOT - PP) * ((float)k / (float)n_neg); // top-k >= k*mean
                float ratio_ub = pos_exp / (pos_exp + neg_lb);
                verdict = (ratio_ub < 6.0e-3f) ? 5.0f : -2.f;  // < e^-5 -> loss==5.0 exactly
            }
            hardLoss[row] = verdict;
        }
    } else if (b < B_ + C_) {
        int c = b - B_;
        if (t == 0) bcnt = 0;
        __syncthreads();
        for (int i = t; i < B_; i += 256)
            if (labels[i] == c) { int pos = atomicAdd(&bcnt, 1); list[pos] = i; }
        __syncthreads();
        int n = bcnt;
        float s0 = 0.f, s1 = 0.f, q0 = 0.f, q1 = 0.f, sc = 0.f;
        for (int j = 0; j < n; j++) {
            int r = list[j];
            const float* p = F + (size_t)r * D_;
            float v0 = p[t], v1 = p[t + 256];
            s0 += v0; s1 += v1; q0 += v0 * v0; q1 += v1 * v1;
        }
        for (int j = t; j < n; j += 256) sc += scores[list[j]];
        float fn = (float)n;
        float safe_n = fmaxf(fn, 1.f);
        float m0 = s0 / safe_n, m1 = s1 / safe_n;
        float dv = fmaxf(fn - 1.f, 1.f);
        float v0 = (q0 - fn * m0 * m0) / dv;
        float v1 = (q1 - fn * m1 * m1) / dv;
        float rv = v0 + v1;
#pragma unroll
        for (int o = 32; o; o >>= 1) { rv += __shfl_xor(rv, o); sc += __shfl_xor(sc, o); }
        if ((t & 63) == 0) { r0[wave] = rv; r1[wave] = sc; }
        __syncthreads();
        if (t == 0) {
            float var_mean = (r0[0] + r0[1] + r0[2] + r0[3]) / 512.f;
            var_mean = fminf(fmaxf(var_mean, 1e-6f), 100.f);
            float target = 1.f / (1.f + expf(-var_mean));
            float mean_s = (r1[0] + r1[1] + r1[2] + r1[3]) / safe_n;
            float d = mean_s - target;
            float bl = fminf(d * d, 2.f);
            blSlot[c] = (fn > 1.f) ? bl : -1.f;
        }
    } else {
        int row = (b - B_ - C_) * 4 + wave;
        const float* pr = psims + (size_t)row * 128;
        bool on = lane < L_;
        float o  = on ? pr[lane]      : -1e30f;
        float nn = on ? pr[L_ + lane] : -1e30f;
        float mo = o, mn = nn;
#pragma unroll
        for (int s = 32; s; s >>= 1) {
            mo = fmaxf(mo, __shfl_xor(mo, s));
            mn = fmaxf(mn, __shfl_xor(mn, s));
        }
        float eo = on ? __expf(o - mo) : 0.f;
        float en = on ? __expf(nn - mn) : 0.f;
#pragma unroll
        for (int s = 32; s; s >>= 1) { eo += __shfl_xor(eo, s); en += __shfl_xor(en, s); }
        float lo = logf(eo), ln_ = logf(en);
        float olp = o - mo - lo;
        float nlp = nn - mn - ln_;
        float kl = on ? __expf(olp) * (olp - nlp) : 0.f;
#pragma unroll
        for (int s = 32; s; s >>= 1) kl += __shfl_xor(kl, s);
        if (lane == 0) klrow[row] = kl;
    }
}

// ---------------- K_final: slot reduction + in-block exact fallback (rare) ----
__global__ __launch_bounds__(256) void k_final(
    const unsigned short* __restrict__ sims, const int* __restrict__ labels,
    const unsigned long long* __restrict__ maskT, const int* __restrict__ cnt_buf,
    const float* __restrict__ hardLoss, const float* __restrict__ posP,
    const float* __restrict__ blSlot, const float* __restrict__ klrow,
    float* __restrict__ out) {
    __shared__ unsigned sku[8192];
    __shared__ int warr[16][4];
    __shared__ float rr[4]; __shared__ int ri[4];
    __shared__ int fbRows[64]; __shared__ int fbCnt;
    __shared__ float SH_hs; __shared__ int SH_hc;
    int t = threadIdx.x;
    int wave = t >> 6;
    if (t == 0) fbCnt = 0;
    __syncthreads();

    float hs = 0.f, bs = 0.f, ks = 0.f;
    int hc = 0, bc = 0;
    for (int i = t; i < B_; i += 256) {
        float v = hardLoss[i];
        if (v >= 0.f) { hs += v; hc++; }
        else if (v == -2.f) { int p = atomicAdd(&fbCnt, 1); if (p < 64) fbRows[p] = i; }
        ks += klrow[i];
    }
    for (int i = t; i < C_; i += 256) {
        float v = blSlot[i];
        if (v >= 0.f) { bs += v; bc++; }
    }
#pragma unroll
    for (int o = 32; o; o >>= 1) {
        hs += __shfl_xor(hs, o); bs += __shfl_xor(bs, o); ks += __shfl_xor(ks, o);
        hc += __shfl_xor(hc, o); bc += __shfl_xor(bc, o);
    }
    __shared__ float w_hs[4], w_bs[4], w_ks[4]; __shared__ int w_hc[4], w_bc[4];
    if ((t & 63) == 0) { w_hs[wave] = hs; w_bs[wave] = bs; w_ks[wave] = ks;
                         w_hc[wave] = hc; w_bc[wave] = bc; }
    __syncthreads();
    if (t == 0) { SH_hs = w_hs[0] + w_hs[1] + w_hs[2] + w_hs[3];
                  SH_hc = w_hc[0] + w_hc[1] + w_hc[2] + w_hc[3]; }
    __syncthreads();

    // exact fallback for uncertified rows (expected 0; correctness escape hatch)
    int nfb = min(fbCnt, 64);
    for (int fi = 0; fi < nfb; fi++) {
        int row = fbRows[fi];
        int lab = labels[row];
        unsigned long long pm = maskT[(size_t)lab * 256 + t];
        const unsigned short* kr = sims + (size_t)row * M_ + t * 8;
#pragma unroll
        for (int q = 0; q < 8; q++)
            async16(kr + q * 2048, &sku[(q * 256 + t) * 4]);
        __syncthreads();
#pragma unroll
        for (int q = 0; q < 8; q++) {
            unsigned pb = (unsigned)(pm >> (8 * q)) & 0xFFu;
            unsigned base = (unsigned)(q * 256 + t) * 4;
#pragma unroll
            for (int h = 0; h < 4; h++) {
                unsigned w = sku[base + h];
                unsigned lo = w & 0xFFFFu, hi = w >> 16;
                lo = (pb & (1u << (2 * h)))     ? 0u : keytx(lo);
                hi = (pb & (1u << (2 * h + 1))) ? 0u : keytx(hi);
                sku[base + h] = lo | (hi << 16);
            }
        }
        __syncthreads();
        int n_pos = cnt_buf[lab];
        int k = (int)(0.7f * (float)(M_ - n_pos));
        unsigned cur = 0;
        for (int r = 15; r >= 0; r--) {
            unsigned T = cur | (1u << r);
            unsigned Th = T << 16;
            int cnt = 0;
#pragma unroll
            for (int q = 0; q < 8; q++) {
                uint4 w = *(const uint4*)&sku[(unsigned)(q * 256 + t) * 4];
                cnt += __popcll(__ballot(w.x >= Th)) + __popcll(__ballot((w.x & 0xFFFFu) >= T));
                cnt += __popcll(__ballot(w.y >= Th)) + __popcll(__ballot((w.y & 0xFFFFu) >= T));
                cnt += __popcll(__ballot(w.z >= Th)) + __popcll(__ballot((w.z & 0xFFFFu) >= T));
                cnt += __popcll(__ballot(w.w >= Th)) + __popcll(__ballot((w.w & 0xFFFFu) >= T));
            }
            if ((t & 63) == 0) warr[15 - r][wave] = cnt;
            __syncthreads();
            int tt = warr[15 - r][0] + warr[15 - r][1] + warr[15 - r][2] + warr[15 - r][3];
            if (tt >= k) cur = T;
        }
        int cgt = 0; float sgt = 0.f;
#pragma unroll
        for (int q = 0; q < 8; q++) {
            uint4 w = *(const uint4*)&sku[(unsigned)(q * 256 + t) * 4];
#define HALVES(x)                                                              \
            { unsigned hk = (x) >> 16;     if (hk > cur) { cgt++; sgt += __expf(keyval(hk)); } \
              unsigned lk = (x) & 0xFFFFu; if (lk > cur) { cgt++; sgt += __expf(keyval(lk)); } }
            HALVES(w.x) HALVES(w.y) HALVES(w.z) HALVES(w.w)
#undef HALVES
        }
#pragma unroll
        for (int o = 32; o; o >>= 1) { sgt += __shfl_xor(sgt, o); cgt += __shfl_xor(cgt, o); }
        if ((t & 63) == 0) { rr[wave] = sgt; ri[wave] = cgt; }
        __syncthreads();
        if (t == 0) {
            float sumGt = rr[0] + rr[1] + rr[2] + rr[3];
            int   cntGt = ri[0] + ri[1] + ri[2] + ri[3];
            float negExp = sumGt + (float)(k - cntGt) * __expf(keyval(cur));
            float pos_exp = posP[row] / (float)max(n_pos, 1);
            float denom = fmaxf(pos_exp + negExp, 1e-8f);
            float ratio = fminf(fmaxf(pos_exp / denom, 1e-8f), 1.0f);
            float loss = fminf(fmaxf(-logf(ratio), 0.f), 5.f);
            SH_hs += loss; SH_hc += 1;
        }
        __syncthreads();
    }

    if (t == 0) {
        float hard = SH_hs / fmaxf((float)SH_hc, 1.f);
        float BS = w_bs[0] + w_bs[1] + w_bs[2] + w_bs[3];
        int   BC = w_bc[0] + w_bc[1] + w_bc[2] + w_bc[3];
        float boundary = BS / fmaxf((float)BC, 1.f);
        float KS = w_ks[0] + w_ks[1] + w_ks[2] + w_ks[3];
        float kl = fminf(fmaxf(KS / (float)B_, 0.f), 5.f);
        out[0] = hard + 0.1f * boundary + 0.2f * kl;
    }
}

extern "C" void kernel_launch(void* const* d_in, const int* in_sizes, int n_in,
                              void* d_out, int out_size, void* d_ws, size_t ws_size,
                              hipStream_t stream) {
    const float* feat   = (const float*)d_in[0];
    const float* buf    = (const float*)d_in[1];
    const float* protos = (const float*)d_in[2];
    const float* oldp   = (const float*)d_in[3];
    const float* W      = (const float*)d_in[4];
    const float* bb     = (const float*)d_in[5];
    const int* labels   = (const int*)d_in[6];
    const int* blab     = (const int*)d_in[7];
    const int* lc       = (const int*)d_in[8];
    float* out = (float*)d_out;

    char* wsb = (char*)d_ws;
    unsigned short* simb = (unsigned short*)wsb;                        // 32 MiB
    __hip_bfloat16* fbf  = (__hip_bfloat16*)(wsb + 33554432);           // 1 MiB
    __hip_bfloat16* bbf  = (__hip_bfloat16*)(wsb + 34603008);           // 16 MiB
    unsigned long long* maskT = (unsigned long long*)(wsb + 51380224);  // 200 KiB
    __hip_bfloat16* pbf  = (__hip_bfloat16*)(wsb + 51585024);           // 128 KiB
    float* psims = (float*)(wsb + 51716096);                            // 512 KiB
    float* scores   = (float*)(wsb + 52240384);
    int*   cnt_buf  = (int*)(scores + B_);
    float* hardLoss = (float*)(cnt_buf + 128);
    float* posP     = hardLoss + B_;
    float* blSlot   = posP + B_;
    float* klrow    = blSlot + 128;

    k_pre0<<<NB4 + C_ + B_ / 4, 256, 0, stream>>>(feat, buf, protos, oldp, lc, blab, W, bb,
                                                  fbf, bbf, pbf, maskT, cnt_buf, scores);
    dim3 g(129, B_ / TM);
    k_gemm<<<g, 256, 0, stream>>>(fbf, bbf, pbf, simb, psims);
    k_cert_tail<<<B_ + C_ + B_ / 4, 256, 0, stream>>>(simb, labels, maskT, cnt_buf,
                                                      feat, scores, psims,
                                                      hardLoss, posP, blSlot, klrow);
    k_final<<<1, 256, 0, stream>>>(simb, labels, maskT, cnt_buf,
                                   hardLoss, posP, blSlot, klrow, out);
}